// Round 1
// baseline (26248.956 us; speedup 1.0000x reference)
//
#include <hip/hip_runtime.h>
#include <hip/hip_bf16.h>

// ---------------- constants ----------------
#define NFR    2048
#define BATCHN 8
#define NFFT   512
#define HOPSZ  256
#define BINS   257
#define HIDDEN 512
#define HHALF  256
#define NGATES 1024
#define LTXT   512
#define TAUD   524544
#define NEGV  -100000.0f
#define POSV   200000.0f
#define LSTM_NWG 4

using short8 = __attribute__((ext_vector_type(8))) short;
using f32x4  = __attribute__((ext_vector_type(4))) float;

__device__ __forceinline__ unsigned short f2bf(float x) {
  union { float f; unsigned u; } v; v.f = x;
  unsigned u = v.u;
  u += 0x7fffu + ((u >> 16) & 1u);   // round-to-nearest-even
  return (unsigned short)(u >> 16);
}
__device__ __forceinline__ float bf2f(unsigned short h) {
  union { unsigned u; float f; } v; v.u = ((unsigned)h) << 16;
  return v.f;
}
__device__ __forceinline__ float sigm(float x) { return 1.0f / (1.0f + expf(-x)); }

// ---------------- zero fill (instead of memset, 100% capture-safe) ----------------
__global__ __launch_bounds__(256) void zero_kernel(int* p, int n) {
  int i = blockIdx.x * 256 + threadIdx.x;
  if (i < n) p[i] = 0;
}

// ---------------- STFT magnitude + input mean/scale ----------------
// y[(f*8+b)*257 + k] = (|rfft(hann*frame)|[k] + imean[k]) * iscale[k]
__global__ __launch_bounds__(256) void stft_kernel(const float* __restrict__ x,
    const float* __restrict__ imean, const float* __restrict__ iscale,
    float* __restrict__ y)
{
  __shared__ float tab[512];
  __shared__ float xs[512];
  int f = blockIdx.x, b = blockIdx.y, tid = threadIdx.x;
  for (int m = tid; m < 512; m += 256)
    tab[m] = cosf(6.283185307179586e0f / 512.0f * (float)m);
  __syncthreads();
  const float* xb = x + (size_t)b * TAUD + (size_t)f * HOPSZ;
  for (int n = tid; n < 512; n += 256)
    xs[n] = xb[n] * 0.5f * (1.0f - tab[n]);   // periodic hann
  __syncthreads();
  for (int k = tid; k < 257; k += 256) {
    float ar = 0.f, ai = 0.f;
    int m = 0;
    for (int n = 0; n < 512; ++n) {
      float xv = xs[n];
      ar += xv * tab[m];
      ai += xv * tab[(m + 384) & 511];   // sin via cos shift (sign irrelevant for |.|)
      m = (m + k) & 511;
    }
    float mag = sqrtf(ar * ar + ai * ai);
    y[((size_t)f * BATCHN + b) * BINS + k] = (mag + imean[k]) * iscale[k];
  }
}

// ---------------- generic transpose (R,C) -> (C,R), batched ----------------
__global__ __launch_bounds__(256) void transpose_kernel(const float* __restrict__ in,
    float* __restrict__ out, int R, int C, long inBatch, long outBatch)
{
  __shared__ float tile[32][33];
  const float* ib = in + (size_t)blockIdx.z * inBatch;
  float* ob = out + (size_t)blockIdx.z * outBatch;
  int r0 = blockIdx.y * 32, c0 = blockIdx.x * 32;
  int tx = threadIdx.x & 31, ty = threadIdx.x >> 5;  // 8 rows of 32
  for (int i = ty; i < 32; i += 8) {
    int r = r0 + i, c = c0 + tx;
    if (r < R && c < C) tile[i][tx] = ib[(size_t)r * C + c];
  }
  __syncthreads();
  for (int i = ty; i < 32; i += 8) {
    int c = c0 + i, r = r0 + tx;
    if (r < R && c < C) ob[(size_t)c * R + r] = tile[tx][i];
  }
}

// ---------------- fp32 GEMM: C[r][c] = sum_k A[r][k]*B[k][c] (+bias[c]); optional
// A-transform tanh(trA[k]*a+trB[k]) applied while staging (fused BN+tanh) ----------
__device__ __forceinline__ void storeval(float* p, float v) { *p = v; }
__device__ __forceinline__ void storeval(unsigned short* p, float v) { *p = f2bf(v); }

template <typename OutT>
__global__ __launch_bounds__(256) void gemm_kernel(
    const float* __restrict__ A, long lda, long strideA,
    const float* __restrict__ B, long ldb, long strideB,
    OutT* __restrict__ C, long ldc, long strideC,
    int K, const float* __restrict__ bias,
    const float* __restrict__ trA, const float* __restrict__ trB)
{
  __shared__ float As[16][512];
  int bz = blockIdx.z;
  A += (size_t)bz * strideA; B += (size_t)bz * strideB; C += (size_t)bz * strideC;
  int rowb = blockIdx.x * 16;
  int colb = blockIdx.y * 512;
  int tid = threadIdx.x;
  for (int r = 0; r < 16; ++r)
    for (int k = tid; k < K; k += 256) {
      float v = A[(size_t)(rowb + r) * lda + k];
      if (trA) v = tanhf(trA[k] * v + trB[k]);
      As[r][k] = v;
    }
  __syncthreads();
  float acc0[16], acc1[16];
#pragma unroll
  for (int r = 0; r < 16; ++r) { acc0[r] = 0.f; acc1[r] = 0.f; }
  int c0 = colb + tid, c1 = colb + tid + 256;
  for (int k = 0; k < K; ++k) {
    float b0 = B[(size_t)k * ldb + c0];
    float b1 = B[(size_t)k * ldb + c1];
#pragma unroll
    for (int r = 0; r < 16; ++r) {
      acc0[r] = fmaf(As[r][k], b0, acc0[r]);
      acc1[r] = fmaf(As[r][k], b1, acc1[r]);
    }
  }
  float bs0 = bias ? bias[c0] : 0.f;
  float bs1 = bias ? bias[c1] : 0.f;
  for (int r = 0; r < 16; ++r) {
    storeval(C + (size_t)(rowb + r) * ldc + c0, acc0[r] + bs0);
    storeval(C + (size_t)(rowb + r) * ldc + c1, acc1[r] + bs1);
  }
}

// ---------------- BatchNorm (training-mode batch stats) ----------------
__global__ __launch_bounds__(256) void bn_stats_kernel(const float* __restrict__ z,
                                                       float* __restrict__ stats)
{
  int rowb = blockIdx.x * 64;
  int c = threadIdx.x * 2;
  float s0 = 0, s1 = 0, q0 = 0, q1 = 0;
  for (int r = 0; r < 64; ++r) {
    const float* p = z + (size_t)(rowb + r) * 512 + c;
    float v0 = p[0], v1 = p[1];
    s0 += v0; s1 += v1; q0 += v0 * v0; q1 += v1 * v1;
  }
  atomicAdd(&stats[c], s0);       atomicAdd(&stats[c + 1], s1);
  atomicAdd(&stats[512 + c], q0); atomicAdd(&stats[512 + c + 1], q1);
}

__global__ void bn_fin_kernel(float* stats, const float* __restrict__ g,
                              const float* __restrict__ b)
{
  int h = threadIdx.x;  // 512 threads
  float mu  = stats[h] * (1.0f / 16384.0f);
  float var = stats[512 + h] * (1.0f / 16384.0f) - mu * mu;
  float a = g[h] * rsqrtf(var + 1e-5f);
  stats[1024 + h] = a;
  stats[1536 + h] = b[h] - mu * a;
}

// ---------------- text one-hot gate-input gather ----------------
// gin[((l*8+b)*2048) + dir*1024 + j] = twT[dir][idx[b][l]][j] + tb[dir][j]
__global__ __launch_bounds__(256) void text_gin_kernel(const int* __restrict__ idx,
    const float* __restrict__ twT, const float* __restrict__ tb,
    unsigned short* __restrict__ gin)
{
  size_t i = (size_t)blockIdx.x * 256 + threadIdx.x;
  if (i >= (size_t)2 * 512 * 8 * 1024) return;
  int j   = i & 1023;
  int dir = (i >> 10) & 1;
  int b   = (i >> 11) & 7;
  int l   = (int)(i >> 14);
  int v = idx[b * 512 + l];
  float val = twT[((size_t)dir * 44 + v) * 1024 + j] + tb[dir * 1024 + j];
  gin[((size_t)(l * 8 + b)) * 2048 + dir * 1024 + j] = f2bf(val);
}

// ---------------- bidirectional LSTM layer (recurrent part, MFMA) ----------------
// grid = 8 blocks: blockIdx = dir*4 + wg. Each WG owns 64 hidden units (4 gate rows
// each) of its direction; Whh slice lives in LDS as bf16 (XOR-swizzled, k-permuted
// for single-b128 MFMA fragment reads). Per step: gates = gin + h_prev @ WhhT via
// mfma_f32_16x16x32_bf16 (M=batch 8 padded to 16), then c/h update in registers,
// h exchanged through global hbuf + device-scope atomic barrier.
__global__ __launch_bounds__(256) void lstm_kernel(
    const unsigned short* __restrict__ gin,   // [(t*8+b)*2048 + dir*1024 + j]
    const float* __restrict__ whh,            // [dir][1024][256]
    float* __restrict__ out, long ostT, long ostB,
    unsigned short* __restrict__ hbuf,        // [parity][dir][8][256]
    int* ctr, int T)
{
  __shared__ unsigned short whh_lds[256 * 256]; // 128 KiB, rows of 512B, swizzled
  __shared__ unsigned short h_lds[16 * 256];    // 8 KiB  (rows 8..15 stay zero)
  int wg = blockIdx.x & 3, dir = blockIdx.x >> 2;
  int tid = threadIdx.x;
  int lane = tid & 63, w = tid >> 6;

  // stage Whh slice: slice row rr -> global gate row jg = gt*256 + wg*64 + (rr&63)
  // k pre-permuted: store at ks the source k = cc*32 + h*16 + q*4 + jj
  for (int i = tid; i < 256 * 256; i += 256) {
    int rr = i >> 8, ks = i & 255;
    int gt = rr >> 6, ul = rr & 63;
    int jg = gt * 256 + wg * 64 + ul;
    int cc = ks >> 5, q = (ks >> 3) & 3, hh = (ks >> 2) & 1, jj = ks & 3;
    int ksrc = cc * 32 + hh * 16 + q * 4 + jj;
    float v = whh[((size_t)dir * 1024 + jg) * 256 + ksrc];
    int byteoff = rr * 512 + ((2 * ks) ^ ((rr & 7) << 4));
    whh_lds[byteoff >> 1] = f2bf(v);
  }
  for (int i = tid; i < 16 * 256; i += 256) {
    int rr = i >> 8, ks = i & 255;
    int byteoff = rr * 512 + ((2 * ks) ^ ((rr & 7) << 4));
    h_lds[byteoff >> 1] = 0;
  }
  __syncthreads();

  int col = lane & 15, lg = lane >> 4;
  int u_loc = wg * 64 + w * 16 + col;       // hidden-unit index (0..255)
  float cst[4] = {0.f, 0.f, 0.f, 0.f};     // cell state for b = lg*4 + r
  const char* hbase = (const char*)h_lds;
  const char* wbase = (const char*)whh_lds;

  // prologue gin preload for step 0
  unsigned short ginr[16];
  {
    int t0 = dir ? (T - 1) : 0;
    const unsigned short* gp = gin + (size_t)(t0 * 8) * 2048 + dir * 1024;
#pragma unroll
    for (int gt = 0; gt < 4; ++gt)
#pragma unroll
      for (int r = 0; r < 4; ++r) {
        int b = lg * 4 + r; int bb = b < 8 ? b : 7;
        ginr[gt * 4 + r] = gp[(size_t)bb * 2048 + gt * 256 + u_loc];
      }
  }

  for (int s = 0; s < T; ++s) {
    int t = dir ? (T - 1 - s) : s;
    f32x4 acc[4];
#pragma unroll
    for (int gt = 0; gt < 4; ++gt)
#pragma unroll
      for (int r = 0; r < 4; ++r) acc[gt][r] = bf2f(ginr[gt * 4 + r]);

#pragma unroll
    for (int cc = 0; cc < 8; ++cc) {
      int aoff = col * 512 + (((cc * 64) + lg * 16) ^ ((col & 7) << 4));
      short8 av = *(const short8*)(hbase + aoff);
#pragma unroll
      for (int gt = 0; gt < 4; ++gt) {
        int rr = (gt * 4 + w) * 16 + col;
        int boff = rr * 512 + (((cc * 64) + lg * 16) ^ ((rr & 7) << 4));
        short8 bv = *(const short8*)(wbase + boff);
        acc[gt] = __builtin_amdgcn_mfma_f32_16x16x32_bf16(av, bv, acc[gt], 0, 0, 0);
      }
    }

    if (lg < 2) {
#pragma unroll
      for (int r = 0; r < 4; ++r) {
        int b = lg * 4 + r;
        float si = sigm(acc[0][r]);
        float sf = sigm(acc[1][r]);
        float tg = tanhf(acc[2][r]);
        float so = sigm(acc[3][r]);
        float c = sf * cst[r] + si * tg;
        cst[r] = c;
        float h = so * tanhf(c);
        out[(size_t)t * ostT + (size_t)b * ostB + dir * 256 + u_loc] = h;
        hbuf[((size_t)(s & 1) * 2 + dir) * 2048 + b * 256 + u_loc] = f2bf(h);
      }
    }
    if (s == T - 1) break;

    // prefetch next step's gin (latency hides under the barrier spin)
    {
      int tn = dir ? (T - 2 - s) : (s + 1);
      const unsigned short* gp = gin + (size_t)(tn * 8) * 2048 + dir * 1024;
#pragma unroll
      for (int gt = 0; gt < 4; ++gt)
#pragma unroll
        for (int r = 0; r < 4; ++r) {
          int b = lg * 4 + r; int bb = b < 8 ? b : 7;
          ginr[gt * 4 + r] = gp[(size_t)bb * 2048 + gt * 256 + u_loc];
        }
    }

    __threadfence();
    __syncthreads();
    if (tid == 0) {
      atomicAdd(&ctr[s], 1);
      while (__hip_atomic_load(&ctr[s], __ATOMIC_RELAXED,
                               __HIP_MEMORY_SCOPE_AGENT) < 2 * LSTM_NWG)
        __builtin_amdgcn_s_sleep(2);
    }
    __syncthreads();
    __threadfence();

    // rebuild full h_lds from hbuf (k-permuted + swizzled)
    {
      int b = tid >> 5, kc = tid & 31;
      int cc2 = kc >> 2, q = kc & 3;
      const unsigned short* hp =
          hbuf + ((size_t)(s & 1) * 2 + dir) * 2048 + b * 256;
      unsigned short vals[8] __attribute__((aligned(16)));
#pragma unroll
      for (int j = 0; j < 4; ++j) vals[j] = hp[cc2 * 32 + q * 4 + j];
#pragma unroll
      for (int j = 0; j < 4; ++j) vals[4 + j] = hp[cc2 * 32 + 16 + q * 4 + j];
      int byteoff = b * 512 + ((kc * 16) ^ ((b & 7) << 4));
      *(short8*)((char*)h_lds + byteoff) = *(const short8*)vals;
    }
    __syncthreads();
  }
}

// ---------------- DTW (in-place over scores in d_out) ----------------
__global__ __launch_bounds__(256) void dtw_kernel(float* __restrict__ sc)
{
  __shared__ float P[513];
  int b = blockIdx.x, tid = threadIdx.x;
  for (int j = tid; j < 513; j += 256) P[j] = (j == 0) ? POSV : NEGV;
  __syncthreads();
  float* base = sc + (size_t)b * NFR * 512;
  for (int n = 0; n < NFR; ++n) {
    float* row = base + (size_t)n * 512;
    float s0 = row[tid], s1 = row[tid + 256];
    float v0 = s0 + fmaxf(P[tid + 1], P[tid]);
    float v1 = s1 + fmaxf(P[tid + 257], P[tid + 256]);
    __syncthreads();
    P[tid + 1] = v0; P[tid + 257] = v1;
    if (tid == 0) P[0] = NEGV;
    row[tid] = v0; row[tid + 256] = v1;
    __syncthreads();
  }
}

// ---------------- launch ----------------
extern "C" void kernel_launch(void* const* d_in, const int* in_sizes, int n_in,
                              void* d_out, int out_size, void* d_ws, size_t ws_size,
                              hipStream_t stream) {
  const float* x_audio  = (const float*)d_in[0];
  const int*   text_idx = (const int*)d_in[1];
  const float* txt_wih  = (const float*)d_in[2];
  const float* txt_whh  = (const float*)d_in[3];
  const float* txt_b    = (const float*)d_in[4];
  const float* w_s      = (const float*)d_in[5];
  const float* fc1_w    = (const float*)d_in[6];
  const float* bn1_g    = (const float*)d_in[7];
  const float* bn1_b    = (const float*)d_in[8];
  const float* imean    = (const float*)d_in[9];
  const float* iscale   = (const float*)d_in[10];
  const float* ae_wih   = (const float*)d_in[11];
  const float* ae_whh   = (const float*)d_in[12];
  const float* ae_b     = (const float*)d_in[13];

  char* ws = (char*)d_ws;
  size_t off = 0;
  auto alloc = [&](size_t sz) { size_t o = off; off += (sz + 255) & ~255ull; return o; };
  size_t OFF_Y    = alloc(16384ull * 257 * 4);
  size_t OFF_WT   = alloc(257ull * 512 * 4);
  size_t OFF_TWT  = alloc(2ull * 44 * 1024 * 4);
  size_t OFF_WIHT = alloc(512ull * 2048 * 4);
  size_t OFF_Z    = alloc(16384ull * 512 * 4);
  size_t OFF_L1   = alloc(16384ull * 512 * 4);
  size_t OFF_L2   = alloc(16384ull * 512 * 4);
  size_t OFF_TXT  = alloc(8ull * 512 * 512 * 4);
  size_t OFF_GIN  = alloc(16384ull * 2048 * 2);    // bf16; reused later:
  size_t OFF_HTT  = OFF_GIN;                        //  htT (8.4MB)
  size_t OFF_SIDE = OFF_GIN + 8ull * 512 * 512 * 4; //  side (8.4MB)
  size_t OFF_STATS = alloc(2048ull * 4);
  size_t OFF_CTR   = alloc(3ull * 2048 * 4);
  size_t OFF_HBUF  = alloc(2ull * 2 * 8 * 256 * 2);
  (void)ws_size; (void)in_sizes; (void)n_in; (void)out_size; (void)OFF_HBUF;

  float* y       = (float*)(ws + OFF_Y);
  float* wT      = (float*)(ws + OFF_WT);
  float* twT     = (float*)(ws + OFF_TWT);
  float* wihT    = (float*)(ws + OFF_WIHT);
  float* z       = (float*)(ws + OFF_Z);
  float* l1out   = (float*)(ws + OFF_L1);
  float* l2out   = (float*)(ws + OFF_L2);
  float* textout = (float*)(ws + OFF_TXT);
  unsigned short* gin = (unsigned short*)(ws + OFF_GIN);
  float* htT     = (float*)(ws + OFF_HTT);
  float* side    = (float*)(ws + OFF_SIDE);
  float* stats   = (float*)(ws + OFF_STATS);
  int*   ctr0    = (int*)(ws + OFF_CTR);            // text
  int*   ctr1    = (int*)(ws + OFF_CTR + 8192);     // layer 1
  int*   ctr2    = (int*)(ws + OFF_CTR + 16384);    // layer 2
  unsigned short* hbuf = (unsigned short*)(ws + OFF_HBUF);
  float* outp = (float*)d_out;

  // zero stats + barrier counters (32KB contiguous)
  zero_kernel<<<32, 256, 0, stream>>>((int*)(ws + OFF_STATS), 8192);

  // STFT -> y
  stft_kernel<<<dim3(NFR, BATCHN), 256, 0, stream>>>(x_audio, imean, iscale, y);

  // weight transposes
  transpose_kernel<<<dim3(9, 16, 1), 256, 0, stream>>>(fc1_w, wT, 512, 257, 0, 0);
  transpose_kernel<<<dim3(2, 32, 2), 256, 0, stream>>>(txt_wih, twT, 1024, 44,
                                                       1024 * 44, 44 * 1024);

  // fc1: z = y @ wT   (16384 x 257 @ 257 x 512)
  gemm_kernel<float><<<dim3(1024, 1, 1), 256, 0, stream>>>(
      y, 257, 0, wT, 512, 0, z, 512, 0, 257, nullptr, nullptr, nullptr);
  bn_stats_kernel<<<256, 256, 0, stream>>>(z, stats);
  bn_fin_kernel<<<1, 512, 0, stream>>>(stats, bn1_g, bn1_b);

  // text encoder
  text_gin_kernel<<<32768, 256, 0, stream>>>(text_idx, twT, txt_b, gin);
  lstm_kernel<<<8, 256, 0, stream>>>(gin, txt_whh, textout, 512, 512 * 512,
                                     hbuf, ctr0, LTXT);

  // audio LSTM layer 1 (BN+tanh fused into gin GEMM A-staging)
  transpose_kernel<<<dim3(16, 64, 1), 256, 0, stream>>>(ae_wih, wihT, 2048, 512, 0, 0);
  gemm_kernel<unsigned short><<<dim3(1024, 4, 1), 256, 0, stream>>>(
      z, 512, 0, wihT, 2048, 0, gin, 2048, 0, 512, ae_b,
      stats + 1024, stats + 1536);
  lstm_kernel<<<8, 256, 0, stream>>>(gin, ae_whh, l1out, 4096, 512,
                                     hbuf, ctr1, NFR);

  // audio LSTM layer 2
  transpose_kernel<<<dim3(16, 64, 1), 256, 0, stream>>>(
      ae_wih + 2ull * 1024 * 512, wihT, 2048, 512, 0, 0);
  gemm_kernel<unsigned short><<<dim3(1024, 4, 1), 256, 0, stream>>>(
      l1out, 512, 0, wihT, 2048, 0, gin, 2048, 0, 512, ae_b + 2048,
      nullptr, nullptr);
  lstm_kernel<<<8, 256, 0, stream>>>(gin, ae_whh + 2ull * 1024 * 256, l2out,
                                     4096, 512, hbuf, ctr2, NFR);

  // side = w_s @ h_text^T  (per batch), via htT transpose
  transpose_kernel<<<dim3(16, 16, 8), 256, 0, stream>>>(textout, htT, 512, 512,
                                                        512 * 512, 512 * 512);
  gemm_kernel<float><<<dim3(32, 1, 8), 256, 0, stream>>>(
      w_s, 512, 0, htT, 512, 512 * 512, side, 512, 512 * 512, 512,
      nullptr, nullptr, nullptr);

  // scores = x @ side  (per batch) -> d_out, then DTW in-place
  gemm_kernel<float><<<dim3(128, 1, 8), 256, 0, stream>>>(
      l2out, 4096, 512, side, 512, 512 * 512, outp, 512, (long)NFR * 512, 512,
      nullptr, nullptr, nullptr);
  dtw_kernel<<<8, 256, 0, stream>>>(outp);
}

// Round 3
// 13544.344 us; speedup vs baseline: 1.9380x; 1.9380x over previous
//
#include <hip/hip_runtime.h>
#include <hip/hip_bf16.h>

// ---------------- constants ----------------
#define NFR    2048
#define BATCHN 8
#define NFFT   512
#define HOPSZ  256
#define BINS   257
#define HIDDEN 512
#define LTXT   512
#define TAUD   524544
#define NEGV  -100000.0f
#define POSV   200000.0f

using short8 = __attribute__((ext_vector_type(8))) short;
using u16x8  = __attribute__((ext_vector_type(8))) unsigned short;
using f32x4  = __attribute__((ext_vector_type(4))) float;

__device__ __forceinline__ unsigned short f2bf(float x) {
  union { float f; unsigned u; } v; v.f = x;
  unsigned u = v.u;
  u += 0x7fffu + ((u >> 16) & 1u);   // round-to-nearest-even
  return (unsigned short)(u >> 16);
}
__device__ __forceinline__ float bf2f(unsigned short h) {
  union { unsigned u; float f; } v; v.u = ((unsigned)h) << 16;
  return v.f;
}

// fp8 e4m3fn encode (software fallback), round-to-nearest-even
__device__ __forceinline__ unsigned f2fp8_sw(float x) {
  union { float f; unsigned u; } v; v.f = x;
  unsigned s = (v.u >> 24) & 0x80u;
  float a = fabsf(x);
  if (!(a > 0.f)) return s;                    // zero / nan->0
  if (a > 448.f) return s | 0x7e;              // clamp to max finite
  int E = (int)((v.u >> 23) & 0xff) - 127;
  if (E < -6) {                                // subnormal range
    int q = (int)(a * 512.f + 0.5f);
    if (q > 7) return s | 0x08;
    return s | (unsigned)q;
  }
  unsigned m = v.u & 0x7fffffu;
  unsigned mr = m + 0x7ffffu + ((m >> 20) & 1u);
  if (mr >= 0x800000u) { mr -= 0x800000u; E += 1; if (E > 8) return s | 0x7e; }
  return s | ((unsigned)(E + 7) << 3) | (mr >> 20);
}

template <bool HI>
__device__ __forceinline__ int pk_fp8(float a, float b, int old) {
#if __has_builtin(__builtin_amdgcn_cvt_pk_fp8_f32)
  return __builtin_amdgcn_cvt_pk_fp8_f32(a, b, old, HI);
#else
  unsigned pk = f2fp8_sw(a) | (f2fp8_sw(b) << 8);
  return HI ? ((old & 0x0000ffff) | (int)(pk << 16))
            : ((old & 0xffff0000) | (int)pk);
#endif
}
__device__ __forceinline__ unsigned char f2fp8(float x) {
  return (unsigned char)(pk_fp8<false>(x, x, 0) & 0xff);
}

__device__ __forceinline__ float fsigm(float x) {
  return __builtin_amdgcn_rcpf(1.f + __expf(-x));
}
__device__ __forceinline__ float ftanh(float x) {
  return 2.f * __builtin_amdgcn_rcpf(1.f + __expf(-2.f * x)) - 1.f;
}

// gin2 blocked layout: per (t, dir, w): 1024 bf16 = [lg(2)|pad..4][col(16)][uh(2)][gt(4)][r(4)]
__device__ __forceinline__ size_t gin2_index(int t, int dir, int b, int gt, int u) {
  int wv = u >> 5, uh = (u >> 4) & 1, cx = u & 15;
  return ((((size_t)t * 2 + dir) * 8 + wv) * 1024) +
         (size_t)((b >> 2) * 16 + cx) * 32 + uh * 16 + gt * 4 + (b & 3);
}

// ---------------- zero fill ----------------
__global__ __launch_bounds__(256) void zero_kernel(int* p, int n) {
  int i = blockIdx.x * 256 + threadIdx.x;
  if (i < n) p[i] = 0;
}

// ---------------- STFT magnitude + input mean/scale ----------------
__global__ __launch_bounds__(256) void stft_kernel(const float* __restrict__ x,
    const float* __restrict__ imean, const float* __restrict__ iscale,
    float* __restrict__ y)
{
  __shared__ float tab[512];
  __shared__ float xs[512];
  int f = blockIdx.x, b = blockIdx.y, tid = threadIdx.x;
  for (int m = tid; m < 512; m += 256)
    tab[m] = cosf(6.283185307179586e0f / 512.0f * (float)m);
  __syncthreads();
  const float* xb = x + (size_t)b * TAUD + (size_t)f * HOPSZ;
  for (int n = tid; n < 512; n += 256)
    xs[n] = xb[n] * 0.5f * (1.0f - tab[n]);   // periodic hann
  __syncthreads();
  for (int k = tid; k < 257; k += 256) {
    float ar = 0.f, ai = 0.f;
    int m = 0;
    for (int n = 0; n < 512; ++n) {
      float xv = xs[n];
      ar += xv * tab[m];
      ai += xv * tab[(m + 384) & 511];
      m = (m + k) & 511;
    }
    float mag = sqrtf(ar * ar + ai * ai);
    y[((size_t)f * BATCHN + b) * BINS + k] = (mag + imean[k]) * iscale[k];
  }
}

// ---------------- generic transpose ----------------
__global__ __launch_bounds__(256) void transpose_kernel(const float* __restrict__ in,
    float* __restrict__ out, int R, int C, long inBatch, long outBatch)
{
  __shared__ float tile[32][33];
  const float* ib = in + (size_t)blockIdx.z * inBatch;
  float* ob = out + (size_t)blockIdx.z * outBatch;
  int r0 = blockIdx.y * 32, c0 = blockIdx.x * 32;
  int tx = threadIdx.x & 31, ty = threadIdx.x >> 5;
  for (int i = ty; i < 32; i += 8) {
    int r = r0 + i, c = c0 + tx;
    if (r < R && c < C) tile[i][tx] = ib[(size_t)r * C + c];
  }
  __syncthreads();
  for (int i = ty; i < 32; i += 8) {
    int c = c0 + i, r = r0 + tx;
    if (r < R && c < C) ob[(size_t)c * R + r] = tile[tx][i];
  }
}

// ---------------- fp32 GEMM (+fused BN-tanh on A, optional gin2-layout store) ----
__device__ __forceinline__ void storeval(float* p, float v) { *p = v; }
__device__ __forceinline__ void storeval(unsigned short* p, float v) { *p = f2bf(v); }

template <typename OutT>
__global__ __launch_bounds__(256) void gemm_kernel(
    const float* __restrict__ A, long lda, long strideA,
    const float* __restrict__ B, long ldb, long strideB,
    OutT* __restrict__ C, long ldc, long strideC,
    int K, const float* __restrict__ bias,
    const float* __restrict__ trA, const float* __restrict__ trB, int ginmode)
{
  __shared__ float As[16][512];
  int bz = blockIdx.z;
  A += (size_t)bz * strideA; B += (size_t)bz * strideB; C += (size_t)bz * strideC;
  int rowb = blockIdx.x * 16;
  int colb = blockIdx.y * 512;
  int tid = threadIdx.x;
  for (int r = 0; r < 16; ++r)
    for (int k = tid; k < K; k += 256) {
      float v = A[(size_t)(rowb + r) * lda + k];
      if (trA) v = tanhf(trA[k] * v + trB[k]);
      As[r][k] = v;
    }
  __syncthreads();
  float acc0[16], acc1[16];
#pragma unroll
  for (int r = 0; r < 16; ++r) { acc0[r] = 0.f; acc1[r] = 0.f; }
  int c0 = colb + tid, c1 = colb + tid + 256;
  for (int k = 0; k < K; ++k) {
    float b0 = B[(size_t)k * ldb + c0];
    float b1 = B[(size_t)k * ldb + c1];
#pragma unroll
    for (int r = 0; r < 16; ++r) {
      acc0[r] = fmaf(As[r][k], b0, acc0[r]);
      acc1[r] = fmaf(As[r][k], b1, acc1[r]);
    }
  }
  float bs0 = bias ? bias[c0] : 0.f;
  float bs1 = bias ? bias[c1] : 0.f;
  if (ginmode) {
    unsigned short* Cg = (unsigned short*)C;
    for (int r = 0; r < 16; ++r) {
      int row = rowb + r; int t = row >> 3; int b = row & 7;
      { int dir = c0 >> 10, j = c0 & 1023;
        Cg[gin2_index(t, dir, b, j >> 8, j & 255)] = f2bf(acc0[r] + bs0); }
      { int dir = c1 >> 10, j = c1 & 1023;
        Cg[gin2_index(t, dir, b, j >> 8, j & 255)] = f2bf(acc1[r] + bs1); }
    }
  } else {
    for (int r = 0; r < 16; ++r) {
      storeval(C + (size_t)(rowb + r) * ldc + c0, acc0[r] + bs0);
      storeval(C + (size_t)(rowb + r) * ldc + c1, acc1[r] + bs1);
    }
  }
}

// ---------------- BatchNorm (training-mode batch stats) ----------------
__global__ __launch_bounds__(256) void bn_stats_kernel(const float* __restrict__ z,
                                                       float* __restrict__ stats)
{
  int rowb = blockIdx.x * 64;
  int c = threadIdx.x * 2;
  float s0 = 0, s1 = 0, q0 = 0, q1 = 0;
  for (int r = 0; r < 64; ++r) {
    const float* p = z + (size_t)(rowb + r) * 512 + c;
    float v0 = p[0], v1 = p[1];
    s0 += v0; s1 += v1; q0 += v0 * v0; q1 += v1 * v1;
  }
  atomicAdd(&stats[c], s0);       atomicAdd(&stats[c + 1], s1);
  atomicAdd(&stats[512 + c], q0); atomicAdd(&stats[512 + c + 1], q1);
}

__global__ void bn_fin_kernel(float* stats, const float* __restrict__ g,
                              const float* __restrict__ b)
{
  int h = threadIdx.x;  // 512 threads
  float mu  = stats[h] * (1.0f / 16384.0f);
  float var = stats[512 + h] * (1.0f / 16384.0f) - mu * mu;
  float a = g[h] * rsqrtf(var + 1e-5f);
  stats[1024 + h] = a;
  stats[1536 + h] = b[h] - mu * a;
}

// ---------------- text one-hot gate-input gather (gin2 layout) ----------------
__global__ __launch_bounds__(256) void text_gin_kernel(const int* __restrict__ idx,
    const float* __restrict__ twT, const float* __restrict__ tb,
    unsigned short* __restrict__ gin2t)
{
  size_t i = (size_t)blockIdx.x * 256 + threadIdx.x;
  if (i >= (size_t)LTXT * 8 * 2048) return;
  int j   = i & 1023;
  int dir = (i >> 10) & 1;
  int b   = (i >> 11) & 7;
  int l   = (int)(i >> 14);
  int v = idx[b * 512 + l];
  float val = twT[((size_t)dir * 44 + v) * 1024 + j] + tb[dir * 1024 + j];
  gin2t[gin2_index(l, dir, b, j >> 8, j & 255)] = f2bf(val);
}

// ---------------- single-WG-per-direction LSTM (fp8 MFMA, weights in VGPRs) -----
// grid = 2*njobs blocks of 512 threads (8 waves). block = (job, dir).
// Wave w owns units [w*32, w*32+32) x 4 gates. Whh resident as fp8 fragments in
// registers (128 VGPRs/wave). h kept as fp8 in LDS (double-buffered, XOR-swizzled).
// A and B fragments use the SAME natural contiguous-k convention -> any hardware
// k-permutation cancels (validated for bf16 in round 0).
__global__ __launch_bounds__(512, 2) void lstm_kernel(
    const unsigned short* __restrict__ gA, const float* __restrict__ whA,
    float* __restrict__ outA, long ostTA, long ostBA, int TA,
    const unsigned short* __restrict__ gB, const float* __restrict__ whB,
    float* __restrict__ outB, long ostTB, long ostBB, int TB)
{
  __shared__ unsigned char hlds[2][4096];   // [parity][b(16)][u(256)] fp8, swizzled
  int job = blockIdx.x >> 1, dir = blockIdx.x & 1;
  const unsigned short* gin2 = job ? gB : gA;
  const float* whh = job ? whB : whA;
  float* out = job ? outB : outA;
  long ostT = job ? ostTB : ostTA;
  long ostB = job ? ostBB : ostBA;
  int T = job ? TB : TA;

  int tid = threadIdx.x;
  int w = tid >> 6;
  int lane = tid & 63;
  int col = lane & 15, lg = lane >> 4;

  // ---- stage Whh -> fp8 register fragments (one-time) ----
  // tile n = gt*2+uh: rows gt*256 + w*32 + uh*16 + col ; element j = k cc*32+lg*8+j
  long fb[8][8];
  {
    const float* wb = whh + (size_t)dir * 1024 * 256;
#pragma unroll
    for (int n = 0; n < 8; ++n) {
      int gt = n >> 1, uh = n & 1;
      const float* wr = wb + (size_t)(gt * 256 + w * 32 + uh * 16 + col) * 256 + lg * 8;
#pragma unroll
      for (int cc = 0; cc < 8; ++cc) {
        const float* p = wr + cc * 32;
        int lo = 0, hi = 0;
        lo = pk_fp8<false>(p[0], p[1], lo);
        lo = pk_fp8<true >(p[2], p[3], lo);
        hi = pk_fp8<false>(p[4], p[5], hi);
        hi = pk_fp8<true >(p[6], p[7], hi);
        fb[n][cc] = (long)(unsigned)lo | ((long)hi << 32);
      }
    }
  }

  {  // zero h buffers
    int* hz = (int*)hlds;
    for (int i = tid; i < 2048; i += 512) hz[i] = 0;
  }
  __syncthreads();

  float cst[2][4] = {{0.f,0.f,0.f,0.f},{0.f,0.f,0.f,0.f}};
  u16x8 gr[4];

  // prologue gin load (step 0)
  {
    int t0 = dir ? (T - 1) : 0;
    if (lg < 2) {
      const u16x8* gp = (const u16x8*)(gin2 +
          (((size_t)t0 * 2 + dir) * 8 + w) * 1024 + (size_t)(lg * 16 + col) * 32);
      gr[0] = gp[0]; gr[1] = gp[1]; gr[2] = gp[2]; gr[3] = gp[3];
    }
  }

  for (int s = 0; s < T; ++s) {
    int t = dir ? (T - 1 - s) : s;
    int p = s & 1;

    // A fragments: h[b=col][k octet lg] from hlds[p]
    long fa[8];
#pragma unroll
    for (int cc = 0; cc < 8; ++cc) {
      int off = col * 256 + (((cc * 32) + lg * 8) ^ ((col & 7) << 4));
      fa[cc] = *(const long*)(&hlds[p][0] + off);
    }

    // acc init from gin (rows 8..15 are padding -> 0)
    f32x4 acc[8];
#pragma unroll
    for (int n = 0; n < 8; ++n) {
      int gt = n >> 1, uh = n & 1;
      int ch = uh * 2 + (gt >> 1);
#pragma unroll
      for (int r = 0; r < 4; ++r) {
        int e = (gt & 1) * 4 + r;
        float gv = bf2f(gr[ch][e]);
        acc[n][r] = (lg < 2) ? gv : 0.f;
      }
    }

    // prefetch next step's gin early (hides under MFMA + nonlinearity)
    if (s + 1 < T && lg < 2) {
      int tn = dir ? (T - 2 - s) : (s + 1);
      const u16x8* gp = (const u16x8*)(gin2 +
          (((size_t)tn * 2 + dir) * 8 + w) * 1024 + (size_t)(lg * 16 + col) * 32);
      gr[0] = gp[0]; gr[1] = gp[1]; gr[2] = gp[2]; gr[3] = gp[3];
    }

#pragma unroll
    for (int cc = 0; cc < 8; ++cc) {
#pragma unroll
      for (int n = 0; n < 8; ++n) {
        acc[n] = __builtin_amdgcn_mfma_f32_16x16x32_fp8_fp8(fa[cc], fb[n][cc],
                                                            acc[n], 0, 0, 0);
      }
    }

    if (lg < 2) {
#pragma unroll
      for (int uh = 0; uh < 2; ++uh) {
#pragma unroll
        for (int r = 0; r < 4; ++r) {
          int b = lg * 4 + r;
          float gi = fsigm(acc[0 * 2 + uh][r]);
          float gf = fsigm(acc[1 * 2 + uh][r]);
          float gg = ftanh(acc[2 * 2 + uh][r]);
          float go = fsigm(acc[3 * 2 + uh][r]);
          float c = gf * cst[uh][r] + gi * gg;
          cst[uh][r] = c;
          float h = go * ftanh(c);
          int u = w * 32 + uh * 16 + col;
          out[(size_t)t * ostT + (size_t)b * ostB + dir * 256 + u] = h;
          int hoff = b * 256 + (u ^ ((b & 7) << 4));
          hlds[p ^ 1][hoff] = f2fp8(h);
        }
      }
    }
    __syncthreads();
  }
}

// ---------------- DTW (in-place over scores in d_out) ----------------
__global__ __launch_bounds__(256) void dtw_kernel(float* __restrict__ sc)
{
  __shared__ float P[513];
  int b = blockIdx.x, tid = threadIdx.x;
  for (int j = tid; j < 513; j += 256) P[j] = (j == 0) ? POSV : NEGV;
  __syncthreads();
  float* base = sc + (size_t)b * NFR * 512;
  for (int n = 0; n < NFR; ++n) {
    float* row = base + (size_t)n * 512;
    float s0 = row[tid], s1 = row[tid + 256];
    float v0 = s0 + fmaxf(P[tid + 1], P[tid]);
    float v1 = s1 + fmaxf(P[tid + 257], P[tid + 256]);
    __syncthreads();
    P[tid + 1] = v0; P[tid + 257] = v1;
    if (tid == 0) P[0] = NEGV;
    row[tid] = v0; row[tid + 256] = v1;
    __syncthreads();
  }
}

// ---------------- launch ----------------
extern "C" void kernel_launch(void* const* d_in, const int* in_sizes, int n_in,
                              void* d_out, int out_size, void* d_ws, size_t ws_size,
                              hipStream_t stream) {
  const float* x_audio  = (const float*)d_in[0];
  const int*   text_idx = (const int*)d_in[1];
  const float* txt_wih  = (const float*)d_in[2];
  const float* txt_whh  = (const float*)d_in[3];
  const float* txt_b    = (const float*)d_in[4];
  const float* w_s      = (const float*)d_in[5];
  const float* fc1_w    = (const float*)d_in[6];
  const float* bn1_g    = (const float*)d_in[7];
  const float* bn1_b    = (const float*)d_in[8];
  const float* imean    = (const float*)d_in[9];
  const float* iscale   = (const float*)d_in[10];
  const float* ae_wih   = (const float*)d_in[11];
  const float* ae_whh   = (const float*)d_in[12];
  const float* ae_b     = (const float*)d_in[13];

  char* ws = (char*)d_ws;
  size_t off = 0;
  auto alloc = [&](size_t sz) { size_t o = off; off += (sz + 255) & ~255ull; return o; };
  size_t OFF_Y    = alloc(16384ull * 257 * 4);
  size_t OFF_WT   = alloc(257ull * 512 * 4);
  size_t OFF_TWT  = alloc(2ull * 44 * 1024 * 4);
  size_t OFF_WIHT = alloc(512ull * 2048 * 4);
  size_t OFF_Z    = alloc(16384ull * 512 * 4);
  size_t OFF_L1   = alloc(16384ull * 512 * 4);
  size_t OFF_L2   = alloc(16384ull * 512 * 4);   // also reused as gin2_text
  size_t OFF_TXT  = alloc(8ull * 512 * 512 * 4);
  size_t OFF_GIN  = alloc(16384ull * 2048 * 2);  // gin2_audio; reused later:
  size_t OFF_HTT  = OFF_GIN;                      //  htT (8.4MB)
  size_t OFF_SIDE = OFF_GIN + 8ull * 512 * 512 * 4; //  side (8.4MB)
  size_t OFF_STATS = alloc(2048ull * 4);
  (void)ws_size; (void)in_sizes; (void)n_in; (void)out_size;

  float* y       = (float*)(ws + OFF_Y);
  float* wT      = (float*)(ws + OFF_WT);
  float* twT     = (float*)(ws + OFF_TWT);
  float* wihT    = (float*)(ws + OFF_WIHT);
  float* z       = (float*)(ws + OFF_Z);
  float* l1out   = (float*)(ws + OFF_L1);
  float* l2out   = (float*)(ws + OFF_L2);
  float* textout = (float*)(ws + OFF_TXT);
  unsigned short* gin2a = (unsigned short*)(ws + OFF_GIN);
  unsigned short* gin2t = (unsigned short*)(ws + OFF_L2);  // dead until lstm2 out
  float* htT     = (float*)(ws + OFF_HTT);
  float* side    = (float*)(ws + OFF_SIDE);
  float* stats   = (float*)(ws + OFF_STATS);
  float* outp = (float*)d_out;

  zero_kernel<<<8, 256, 0, stream>>>((int*)(ws + OFF_STATS), 2048);

  stft_kernel<<<dim3(NFR, BATCHN), 256, 0, stream>>>(x_audio, imean, iscale, y);

  transpose_kernel<<<dim3(9, 16, 1), 256, 0, stream>>>(fc1_w, wT, 512, 257, 0, 0);
  transpose_kernel<<<dim3(2, 32, 2), 256, 0, stream>>>(txt_wih, twT, 1024, 44,
                                                       1024 * 44, 44 * 1024);

  // fc1: z = y @ wT
  gemm_kernel<float><<<dim3(1024, 1, 1), 256, 0, stream>>>(
      y, 257, 0, wT, 512, 0, z, 512, 0, 257, nullptr, nullptr, nullptr, 0);
  bn_stats_kernel<<<256, 256, 0, stream>>>(z, stats);
  bn_fin_kernel<<<1, 512, 0, stream>>>(stats, bn1_g, bn1_b);

  // text gin (gin2 layout)
  text_gin_kernel<<<32768, 256, 0, stream>>>(text_idx, twT, txt_b, gin2t);

  // audio layer-1 gin (BN+tanh fused into A staging), gin2 layout
  transpose_kernel<<<dim3(16, 64, 1), 256, 0, stream>>>(ae_wih, wihT, 2048, 512, 0, 0);
  gemm_kernel<unsigned short><<<dim3(1024, 4, 1), 256, 0, stream>>>(
      z, 512, 0, wihT, 2048, 0, gin2a, 0, 0, 512, ae_b,
      stats + 1024, stats + 1536, 1);

  // fused launch: audio layer-1 (job 0) + text encoder (job 1)
  lstm_kernel<<<4, 512, 0, stream>>>(
      gin2a, ae_whh, l1out, 4096, 512, NFR,
      gin2t, txt_whh, textout, 512, 512 * 512, LTXT);

  // audio layer-2 gin
  transpose_kernel<<<dim3(16, 64, 1), 256, 0, stream>>>(
      ae_wih + 2ull * 1024 * 512, wihT, 2048, 512, 0, 0);
  gemm_kernel<unsigned short><<<dim3(1024, 4, 1), 256, 0, stream>>>(
      l1out, 512, 0, wihT, 2048, 0, gin2a, 0, 0, 512, ae_b + 2048,
      nullptr, nullptr, 1);

  lstm_kernel<<<2, 512, 0, stream>>>(
      gin2a, ae_whh + 2ull * 1024 * 256, l2out, 4096, 512, NFR,
      gin2a, ae_whh + 2ull * 1024 * 256, l2out, 4096, 512, NFR);

  // side = w_s @ h_text^T  (per batch)
  transpose_kernel<<<dim3(16, 16, 8), 256, 0, stream>>>(textout, htT, 512, 512,
                                                        512 * 512, 512 * 512);
  gemm_kernel<float><<<dim3(32, 1, 8), 256, 0, stream>>>(
      w_s, 512, 0, htT, 512, 512 * 512, side, 512, 512 * 512, 512,
      nullptr, nullptr, nullptr, 0);

  // scores = x @ side -> d_out, then DTW in-place
  gemm_kernel<float><<<dim3(128, 1, 8), 256, 0, stream>>>(
      l2out, 4096, 512, side, 512, 512 * 512, outp, 512, (long)NFR * 512, 512,
      nullptr, nullptr, nullptr, 0);
  dtw_kernel<<<8, 256, 0, stream>>>(outp);
}

// Round 5
// 9544.553 us; speedup vs baseline: 2.7502x; 1.4191x over previous
//
#include <hip/hip_runtime.h>
#include <hip/hip_bf16.h>

// ---------------- constants ----------------
#define NFR    2048
#define BATCHN 8
#define NFFT   512
#define HOPSZ  256
#define BINS   257
#define HIDDEN 512
#define LTXT   512
#define TAUD   524544
#define NEGV  -100000.0f
#define POSV   200000.0f

using short8 = __attribute__((ext_vector_type(8))) short;
using u16x8  = __attribute__((ext_vector_type(8))) unsigned short;
using f32x4  = __attribute__((ext_vector_type(4))) float;
using int4v  = __attribute__((ext_vector_type(4))) int;

__device__ __forceinline__ unsigned short f2bf(float x) {
  union { float f; unsigned u; } v; v.f = x;
  unsigned u = v.u;
  u += 0x7fffu + ((u >> 16) & 1u);   // round-to-nearest-even
  return (unsigned short)(u >> 16);
}
__device__ __forceinline__ float bf2f(unsigned short h) {
  union { unsigned u; float f; } v; v.u = ((unsigned)h) << 16;
  return v.f;
}

__device__ __forceinline__ float fsigm(float x) {
  return __builtin_amdgcn_rcpf(1.f + __expf(-x));
}
__device__ __forceinline__ float ftanh(float x) {
  return 2.f * __builtin_amdgcn_rcpf(1.f + __expf(-2.f * x)) - 1.f;
}

// gin2 blocked layout (per t,dir: 16 wave-chunks of 512 bf16; per lane 16B chunk):
// idx = ((t*2+dir)*16 + w)*512 + (((bh*16+col)*2 + rp)*4 + gt)*2 + rr
// where u = w*16+col, b = bh*4 + rp*2 + rr
__device__ __forceinline__ size_t gin2_index(int t, int dir, int b, int gt, int u) {
  int w = u >> 4, col = u & 15;
  int bh = b >> 2, rp = (b >> 1) & 1, rr = b & 1;
  return (((size_t)t * 2 + dir) * 16 + w) * 512 +
         (size_t)((((bh * 16 + col) * 2 + rp) * 4 + gt) * 2 + rr);
}

// ---------------- zero fill ----------------
__global__ __launch_bounds__(256) void zero_kernel(int* p, int n) {
  int i = blockIdx.x * 256 + threadIdx.x;
  if (i < n) p[i] = 0;
}

// ---------------- STFT magnitude + input mean/scale ----------------
__global__ __launch_bounds__(256) void stft_kernel(const float* __restrict__ x,
    const float* __restrict__ imean, const float* __restrict__ iscale,
    float* __restrict__ y)
{
  __shared__ float tab[512];
  __shared__ float xs[512];
  int f = blockIdx.x, b = blockIdx.y, tid = threadIdx.x;
  for (int m = tid; m < 512; m += 256)
    tab[m] = cosf(6.283185307179586e0f / 512.0f * (float)m);
  __syncthreads();
  const float* xb = x + (size_t)b * TAUD + (size_t)f * HOPSZ;
  for (int n = tid; n < 512; n += 256)
    xs[n] = xb[n] * 0.5f * (1.0f - tab[n]);   // periodic hann
  __syncthreads();
  for (int k = tid; k < 257; k += 256) {
    float ar = 0.f, ai = 0.f;
    int m = 0;
    for (int n = 0; n < 512; ++n) {
      float xv = xs[n];
      ar += xv * tab[m];
      ai += xv * tab[(m + 384) & 511];
      m = (m + k) & 511;
    }
    float mag = sqrtf(ar * ar + ai * ai);
    y[((size_t)f * BATCHN + b) * BINS + k] = (mag + imean[k]) * iscale[k];
  }
}

// ---------------- generic transpose ----------------
__global__ __launch_bounds__(256) void transpose_kernel(const float* __restrict__ in,
    float* __restrict__ out, int R, int C, long inBatch, long outBatch)
{
  __shared__ float tile[32][33];
  const float* ib = in + (size_t)blockIdx.z * inBatch;
  float* ob = out + (size_t)blockIdx.z * outBatch;
  int r0 = blockIdx.y * 32, c0 = blockIdx.x * 32;
  int tx = threadIdx.x & 31, ty = threadIdx.x >> 5;
  for (int i = ty; i < 32; i += 8) {
    int r = r0 + i, c = c0 + tx;
    if (r < R && c < C) tile[i][tx] = ib[(size_t)r * C + c];
  }
  __syncthreads();
  for (int i = ty; i < 32; i += 8) {
    int c = c0 + i, r = r0 + tx;
    if (r < R && c < C) ob[(size_t)c * R + r] = tile[tx][i];
  }
}

// ---------------- fp32 GEMM (+fused BN-tanh on A, optional gin2-layout store) ----
__device__ __forceinline__ void storeval(float* p, float v) { *p = v; }
__device__ __forceinline__ void storeval(unsigned short* p, float v) { *p = f2bf(v); }

template <typename OutT>
__global__ __launch_bounds__(256) void gemm_kernel(
    const float* __restrict__ A, long lda, long strideA,
    const float* __restrict__ B, long ldb, long strideB,
    OutT* __restrict__ C, long ldc, long strideC,
    int K, const float* __restrict__ bias,
    const float* __restrict__ trA, const float* __restrict__ trB, int ginmode)
{
  __shared__ float As[16][512];
  int bz = blockIdx.z;
  A += (size_t)bz * strideA; B += (size_t)bz * strideB; C += (size_t)bz * strideC;
  int rowb = blockIdx.x * 16;
  int colb = blockIdx.y * 512;
  int tid = threadIdx.x;
  for (int r = 0; r < 16; ++r)
    for (int k = tid; k < K; k += 256) {
      float v = A[(size_t)(rowb + r) * lda + k];
      if (trA) v = tanhf(trA[k] * v + trB[k]);
      As[r][k] = v;
    }
  __syncthreads();
  float acc0[16], acc1[16];
#pragma unroll
  for (int r = 0; r < 16; ++r) { acc0[r] = 0.f; acc1[r] = 0.f; }
  int c0 = colb + tid, c1 = colb + tid + 256;
  for (int k = 0; k < K; ++k) {
    float b0 = B[(size_t)k * ldb + c0];
    float b1 = B[(size_t)k * ldb + c1];
#pragma unroll
    for (int r = 0; r < 16; ++r) {
      acc0[r] = fmaf(As[r][k], b0, acc0[r]);
      acc1[r] = fmaf(As[r][k], b1, acc1[r]);
    }
  }
  float bs0 = bias ? bias[c0] : 0.f;
  float bs1 = bias ? bias[c1] : 0.f;
  if (ginmode) {
    unsigned short* Cg = (unsigned short*)C;
    for (int r = 0; r < 16; ++r) {
      int row = rowb + r; int t = row >> 3; int b = row & 7;
      { int dir = c0 >> 10, j = c0 & 1023;
        Cg[gin2_index(t, dir, b, j >> 8, j & 255)] = f2bf(acc0[r] + bs0); }
      { int dir = c1 >> 10, j = c1 & 1023;
        Cg[gin2_index(t, dir, b, j >> 8, j & 255)] = f2bf(acc1[r] + bs1); }
    }
  } else {
    for (int r = 0; r < 16; ++r) {
      storeval(C + (size_t)(rowb + r) * ldc + c0, acc0[r] + bs0);
      storeval(C + (size_t)(rowb + r) * ldc + c1, acc1[r] + bs1);
    }
  }
}

// ---------------- BatchNorm (training-mode batch stats) ----------------
__global__ __launch_bounds__(256) void bn_stats_kernel(const float* __restrict__ z,
                                                       float* __restrict__ stats)
{
  int rowb = blockIdx.x * 64;
  int c = threadIdx.x * 2;
  float s0 = 0, s1 = 0, q0 = 0, q1 = 0;
  for (int r = 0; r < 64; ++r) {
    const float* p = z + (size_t)(rowb + r) * 512 + c;
    float v0 = p[0], v1 = p[1];
    s0 += v0; s1 += v1; q0 += v0 * v0; q1 += v1 * v1;
  }
  atomicAdd(&stats[c], s0);       atomicAdd(&stats[c + 1], s1);
  atomicAdd(&stats[512 + c], q0); atomicAdd(&stats[512 + c + 1], q1);
}

__global__ void bn_fin_kernel(float* stats, const float* __restrict__ g,
                              const float* __restrict__ b)
{
  int h = threadIdx.x;  // 512 threads
  float mu  = stats[h] * (1.0f / 16384.0f);
  float var = stats[512 + h] * (1.0f / 16384.0f) - mu * mu;
  float a = g[h] * rsqrtf(var + 1e-5f);
  stats[1024 + h] = a;
  stats[1536 + h] = b[h] - mu * a;
}

// ---------------- text one-hot gate-input gather (gin2 layout) ----------------
__global__ __launch_bounds__(256) void text_gin_kernel(const int* __restrict__ idx,
    const float* __restrict__ twT, const float* __restrict__ tb,
    unsigned short* __restrict__ gin2t)
{
  size_t i = (size_t)blockIdx.x * 256 + threadIdx.x;
  if (i >= (size_t)LTXT * 8 * 2048) return;
  int j   = i & 1023;
  int dir = (i >> 10) & 1;
  int b   = (i >> 11) & 7;
  int l   = (int)(i >> 14);
  int v = idx[b * 512 + l];
  float val = twT[((size_t)dir * 44 + v) * 1024 + j] + tb[dir * 1024 + j];
  gin2t[gin2_index(l, dir, b, j >> 8, j & 255)] = f2bf(val);
}

// ---------------- single-WG-per-direction LSTM (i8 MFMA, weights in VGPRs) -----
// grid = 2*njobs blocks of 1024 threads (16 waves). block = (job, dir).
// Wave w owns units [w*16,(w+1)*16) x 4 gates; weights as i8 fragments in 64
// VGPRs/wave (Sw=256). h as i8 (Sh=127) in XOR-swizzled LDS, double-buffered.
// mfma_i32_16x16x64_i8: 16 MFMA/wave/step = 256/CU/step. A and B staged with the
// same lane->k convention (cancellation; validated rounds 0-1). 16-wave blocks
// at <=128 VGPR guarantee exactly 1 block/CU (no packing, no spills).
__global__ __launch_bounds__(1024) void lstm_kernel(
    const unsigned short* __restrict__ gA, const float* __restrict__ whA,
    float* __restrict__ outA, long ostTA, long ostBA, int TA,
    const unsigned short* __restrict__ gB, const float* __restrict__ whB,
    float* __restrict__ outB, long ostTB, long ostBB, int TB)
{
  __shared__ unsigned char hlds[2][16][256];   // [parity][batch row][unit] i8, swizzled
  int job = blockIdx.x >> 1, dir = blockIdx.x & 1;
  const unsigned short* gin2 = job ? gB : gA;
  const float* whh = job ? whB : whA;
  float* out = job ? outB : outA;
  long ostT = job ? ostTB : ostTA;
  long ostB = job ? ostBB : ostBA;
  int T = job ? TB : TA;

  int tid = threadIdx.x;
  int w = tid >> 6;                 // 0..15
  int lane = tid & 63;
  int col = lane & 15, lg = lane >> 4;

  // ---- stage Whh -> i8 register fragments (one-time) ----
  // tile gt: B column c = gate row jg = gt*256 + w*16 + c ; element j = k cc*64+lg*16+j
  int4v fb[4][4];
  {
    const float* wb = whh + (size_t)dir * 1024 * 256;
#pragma unroll
    for (int gt = 0; gt < 4; ++gt) {
      const float* wr = wb + (size_t)(gt * 256 + w * 16 + col) * 256 + lg * 16;
#pragma unroll
      for (int cc = 0; cc < 4; ++cc) {
        const float* p = wr + cc * 64;
        int4v v;
#pragma unroll
        for (int e = 0; e < 4; ++e) {
          unsigned wd = 0;
#pragma unroll
          for (int by = 0; by < 4; ++by) {
            float q = rintf(p[e * 4 + by] * 256.f);
            q = fminf(fmaxf(q, -127.f), 127.f);
            wd |= ((unsigned)((int)q & 255)) << (8 * by);
          }
          v[e] = (int)wd;
        }
        fb[gt][cc] = v;
      }
    }
  }

  {  // zero h buffers (rows 8..15 stay zero forever)
    int* hz = (int*)hlds;
    for (int i = tid; i < 2048; i += 1024) hz[i] = 0;
  }
  __syncthreads();

  float cst0 = 0.f, cst1 = 0.f;        // cell state for b = 2*lg, 2*lg+1
  int b0 = 2 * lg, b1 = 2 * lg + 1;
  int u = w * 16 + col;
  int srcl = col + (lg >> 1) * 16;     // source lane for acc redistribution
  const float invS = 1.f / (256.f * 127.f);
  size_t lanebase = (size_t)(((lg >> 1) * 16 + col) * 2 + (lg & 1)) * 8;

  u16x8 gr;
  {
    int t0 = dir ? (T - 1) : 0;
    gr = *(const u16x8*)(gin2 + (((size_t)t0 * 2 + dir) * 16 + w) * 512 + lanebase);
  }

  for (int s = 0; s < T; ++s) {
    int t = dir ? (T - 1 - s) : s;
    int p = s & 1;

    // A fragments: h[batch=col][k-chunk] from hlds[p] (XOR-swizzled b128 reads)
    int4v fa[4];
#pragma unroll
    for (int cc = 0; cc < 4; ++cc) {
      int off = col * 256 + (((cc * 64) + lg * 16) ^ ((col & 7) << 4));
      fa[cc] = *(const int4v*)((const char*)&hlds[p][0][0] + off);
    }

    int4v acc[4];
#pragma unroll
    for (int gt = 0; gt < 4; ++gt) { int4v z = {0, 0, 0, 0}; acc[gt] = z; }
#pragma unroll
    for (int cc = 0; cc < 4; ++cc) {
#pragma unroll
      for (int gt = 0; gt < 4; ++gt) {
        acc[gt] = __builtin_amdgcn_mfma_i32_16x16x64_i8(fa[cc], fb[gt][cc],
                                                        acc[gt], 0, 0, 0);
      }
    }

    // redistribute acc rows so every lane handles batches {2lg, 2lg+1}
    float g0[4], g1[4];
#pragma unroll
    for (int gt = 0; gt < 4; ++gt) {
      int v0 = __shfl(acc[gt][0], srcl, 64);
      int v1 = __shfl(acc[gt][1], srcl, 64);
      int v2 = __shfl(acc[gt][2], srcl, 64);
      int v3 = __shfl(acc[gt][3], srcl, 64);
      int a0 = (lg & 1) ? v2 : v0;
      int a1 = (lg & 1) ? v3 : v1;
      g0[gt] = bf2f(gr[gt * 2 + 0]) + (float)a0 * invS;
      g1[gt] = bf2f(gr[gt * 2 + 1]) + (float)a1 * invS;
    }

    float gi0 = fsigm(g0[0]), gf0 = fsigm(g0[1]), gg0 = ftanh(g0[2]), go0 = fsigm(g0[3]);
    float gi1 = fsigm(g1[0]), gf1 = fsigm(g1[1]), gg1 = ftanh(g1[2]), go1 = fsigm(g1[3]);
    float c0 = gf0 * cst0 + gi0 * gg0; cst0 = c0;
    float c1 = gf1 * cst1 + gi1 * gg1; cst1 = c1;
    float h0 = go0 * ftanh(c0);
    float h1 = go1 * ftanh(c1);

    out[(size_t)t * ostT + (size_t)b0 * ostB + dir * 256 + u] = h0;
    out[(size_t)t * ostT + (size_t)b1 * ostB + dir * 256 + u] = h1;
    hlds[p ^ 1][b0][u ^ ((b0 & 7) << 4)] = (unsigned char)(int)rintf(h0 * 127.f);
    hlds[p ^ 1][b1][u ^ ((b1 & 7) << 4)] = (unsigned char)(int)rintf(h1 * 127.f);

    // prefetch next step's gin (in flight across barrier + next MFMA phase)
    if (s + 1 < T) {
      int tn = dir ? (T - 2 - s) : (s + 1);
      gr = *(const u16x8*)(gin2 + (((size_t)tn * 2 + dir) * 16 + w) * 512 + lanebase);
    }
    __syncthreads();
  }
}

// ---------------- DTW (in-place over scores in d_out) ----------------
__global__ __launch_bounds__(256) void dtw_kernel(float* __restrict__ sc)
{
  __shared__ float P[513];
  int b = blockIdx.x, tid = threadIdx.x;
  for (int j = tid; j < 513; j += 256) P[j] = (j == 0) ? POSV : NEGV;
  __syncthreads();
  float* base = sc + (size_t)b * NFR * 512;
  for (int n = 0; n < NFR; ++n) {
    float* row = base + (size_t)n * 512;
    float s0 = row[tid], s1 = row[tid + 256];
    float v0 = s0 + fmaxf(P[tid + 1], P[tid]);
    float v1 = s1 + fmaxf(P[tid + 257], P[tid + 256]);
    __syncthreads();
    P[tid + 1] = v0; P[tid + 257] = v1;
    if (tid == 0) P[0] = NEGV;
    row[tid] = v0; row[tid + 256] = v1;
    __syncthreads();
  }
}

// ---------------- launch ----------------
extern "C" void kernel_launch(void* const* d_in, const int* in_sizes, int n_in,
                              void* d_out, int out_size, void* d_ws, size_t ws_size,
                              hipStream_t stream) {
  const float* x_audio  = (const float*)d_in[0];
  const int*   text_idx = (const int*)d_in[1];
  const float* txt_wih  = (const float*)d_in[2];
  const float* txt_whh  = (const float*)d_in[3];
  const float* txt_b    = (const float*)d_in[4];
  const float* w_s      = (const float*)d_in[5];
  const float* fc1_w    = (const float*)d_in[6];
  const float* bn1_g    = (const float*)d_in[7];
  const float* bn1_b    = (const float*)d_in[8];
  const float* imean    = (const float*)d_in[9];
  const float* iscale   = (const float*)d_in[10];
  const float* ae_wih   = (const float*)d_in[11];
  const float* ae_whh   = (const float*)d_in[12];
  const float* ae_b     = (const float*)d_in[13];

  char* ws = (char*)d_ws;
  size_t off = 0;
  auto alloc = [&](size_t sz) { size_t o = off; off += (sz + 255) & ~255ull; return o; };
  size_t OFF_Y    = alloc(16384ull * 257 * 4);
  size_t OFF_WT   = alloc(257ull * 512 * 4);
  size_t OFF_TWT  = alloc(2ull * 44 * 1024 * 4);
  size_t OFF_WIHT = alloc(512ull * 2048 * 4);
  size_t OFF_Z    = alloc(16384ull * 512 * 4);
  size_t OFF_L1   = alloc(16384ull * 512 * 4);
  size_t OFF_L2   = alloc(16384ull * 512 * 4);   // also reused as gin2_text
  size_t OFF_TXT  = alloc(8ull * 512 * 512 * 4);
  size_t OFF_GIN  = alloc(16384ull * 2048 * 2);  // gin2_audio; reused later:
  size_t OFF_HTT  = OFF_GIN;                      //  htT (8.4MB)
  size_t OFF_SIDE = OFF_GIN + 8ull * 512 * 512 * 4; //  side (8.4MB)
  size_t OFF_STATS = alloc(2048ull * 4);
  (void)ws_size; (void)in_sizes; (void)n_in; (void)out_size;

  float* y       = (float*)(ws + OFF_Y);
  float* wT      = (float*)(ws + OFF_WT);
  float* twT     = (float*)(ws + OFF_TWT);
  float* wihT    = (float*)(ws + OFF_WIHT);
  float* z       = (float*)(ws + OFF_Z);
  float* l1out   = (float*)(ws + OFF_L1);
  float* l2out   = (float*)(ws + OFF_L2);
  float* textout = (float*)(ws + OFF_TXT);
  unsigned short* gin2a = (unsigned short*)(ws + OFF_GIN);
  unsigned short* gin2t = (unsigned short*)(ws + OFF_L2);  // dead until lstm2 out
  float* htT     = (float*)(ws + OFF_HTT);
  float* side    = (float*)(ws + OFF_SIDE);
  float* stats   = (float*)(ws + OFF_STATS);
  float* outp = (float*)d_out;

  zero_kernel<<<8, 256, 0, stream>>>((int*)(ws + OFF_STATS), 2048);

  stft_kernel<<<dim3(NFR, BATCHN), 256, 0, stream>>>(x_audio, imean, iscale, y);

  transpose_kernel<<<dim3(9, 16, 1), 256, 0, stream>>>(fc1_w, wT, 512, 257, 0, 0);
  transpose_kernel<<<dim3(2, 32, 2), 256, 0, stream>>>(txt_wih, twT, 1024, 44,
                                                       1024 * 44, 44 * 1024);

  // fc1: z = y @ wT
  gemm_kernel<float><<<dim3(1024, 1, 1), 256, 0, stream>>>(
      y, 257, 0, wT, 512, 0, z, 512, 0, 257, nullptr, nullptr, nullptr, 0);
  bn_stats_kernel<<<256, 256, 0, stream>>>(z, stats);
  bn_fin_kernel<<<1, 512, 0, stream>>>(stats, bn1_g, bn1_b);

  // text gin (gin2 layout)
  text_gin_kernel<<<32768, 256, 0, stream>>>(text_idx, twT, txt_b, gin2t);

  // audio layer-1 gin (BN+tanh fused into A staging), gin2 layout
  transpose_kernel<<<dim3(16, 64, 1), 256, 0, stream>>>(ae_wih, wihT, 2048, 512, 0, 0);
  gemm_kernel<unsigned short><<<dim3(1024, 4, 1), 256, 0, stream>>>(
      z, 512, 0, wihT, 2048, 0, gin2a, 0, 0, 512, ae_b,
      stats + 1024, stats + 1536, 1);

  // fused launch: audio layer-1 (job 0) + text encoder (job 1)
  lstm_kernel<<<4, 1024, 0, stream>>>(
      gin2a, ae_whh, l1out, 4096, 512, NFR,
      gin2t, txt_whh, textout, 512, 512 * 512, LTXT);

  // audio layer-2 gin
  transpose_kernel<<<dim3(16, 64, 1), 256, 0, stream>>>(
      ae_wih + 2ull * 1024 * 512, wihT, 2048, 512, 0, 0);
  gemm_kernel<unsigned short><<<dim3(1024, 4, 1), 256, 0, stream>>>(
      l1out, 512, 0, wihT, 2048, 0, gin2a, 0, 0, 512, ae_b + 2048,
      nullptr, nullptr, 1);

  lstm_kernel<<<2, 1024, 0, stream>>>(
      gin2a, ae_whh + 2ull * 1024 * 256, l2out, 4096, 512, NFR,
      gin2a, ae_whh + 2ull * 1024 * 256, l2out, 4096, 512, NFR);

  // side = w_s @ h_text^T  (per batch)
  transpose_kernel<<<dim3(16, 16, 8), 256, 0, stream>>>(textout, htT, 512, 512,
                                                        512 * 512, 512 * 512);
  gemm_kernel<float><<<dim3(32, 1, 8), 256, 0, stream>>>(
      w_s, 512, 0, htT, 512, 512 * 512, side, 512, 512 * 512, 512,
      nullptr, nullptr, nullptr, 0);

  // scores = x @ side -> d_out, then DTW in-place
  gemm_kernel<float><<<dim3(128, 1, 8), 256, 0, stream>>>(
      l2out, 4096, 512, side, 512, 512 * 512, outp, 512, (long)NFR * 512, 512,
      nullptr, nullptr, nullptr, 0);
  dtw_kernel<<<8, 256, 0, stream>>>(outp);
}

// Round 6
// 9203.165 us; speedup vs baseline: 2.8522x; 1.0371x over previous
//
#include <hip/hip_runtime.h>
#include <hip/hip_bf16.h>

// ---------------- constants ----------------
#define NFR    2048
#define BATCHN 8
#define NFFT   512
#define HOPSZ  256
#define BINS   257
#define HIDDEN 512
#define LTXT   512
#define TAUD   524544
#define NEGV  -100000.0f
#define POSV   200000.0f

using short8 = __attribute__((ext_vector_type(8))) short;
using u16x8  = __attribute__((ext_vector_type(8))) unsigned short;
using f32x4  = __attribute__((ext_vector_type(4))) float;
using int4v  = __attribute__((ext_vector_type(4))) int;

__device__ __forceinline__ unsigned short f2bf(float x) {
  union { float f; unsigned u; } v; v.f = x;
  unsigned u = v.u;
  u += 0x7fffu + ((u >> 16) & 1u);   // round-to-nearest-even
  return (unsigned short)(u >> 16);
}
__device__ __forceinline__ float bf2f(unsigned short h) {
  union { unsigned u; float f; } v; v.u = ((unsigned)h) << 16;
  return v.f;
}

__device__ __forceinline__ float fsigm(float x) {
  return __builtin_amdgcn_rcpf(1.f + __expf(-x));
}
__device__ __forceinline__ float ftanh(float x) {
  return 2.f * __builtin_amdgcn_rcpf(1.f + __expf(-2.f * x)) - 1.f;
}

// gin3 layout: per (t, dir, w): [col(16)][b(8)][gt(4)] bf16 (512 elems per w-chunk).
// Lane (w,col,lg) reads its 2 batches (2lg, 2lg+1) x 4 gates as one 16B load.
__device__ __forceinline__ size_t gin3_index(int t, int dir, int b, int gt, int u) {
  return (((size_t)t * 2 + dir) * 16 + (u >> 4)) * 512 +
         (size_t)((u & 15) * 32 + b * 4 + gt);
}

// ---------------- zero fill ----------------
__global__ __launch_bounds__(256) void zero_kernel(int* p, int n) {
  int i = blockIdx.x * 256 + threadIdx.x;
  if (i < n) p[i] = 0;
}

// ---------------- STFT magnitude + input mean/scale ----------------
__global__ __launch_bounds__(256) void stft_kernel(const float* __restrict__ x,
    const float* __restrict__ imean, const float* __restrict__ iscale,
    float* __restrict__ y)
{
  __shared__ float tab[512];
  __shared__ float xs[512];
  __shared__ float red[4];
  int f = blockIdx.x, b = blockIdx.y, tid = threadIdx.x;
  for (int m = tid; m < 512; m += 256)
    tab[m] = cosf(6.283185307179586e0f / 512.0f * (float)m);
  __syncthreads();
  const float* xb = x + (size_t)b * TAUD + (size_t)f * HOPSZ;
  for (int n = tid; n < 512; n += 256)
    xs[n] = xb[n] * 0.5f * (1.0f - tab[n]);   // periodic hann
  __syncthreads();
  // bins 0..255 (one per thread)
  {
    int k = tid;
    float ar = 0.f, ai = 0.f;
    int m = 0;
    for (int n = 0; n < 512; ++n) {
      float xv = xs[n];
      ar += xv * tab[m];
      ai += xv * tab[(m + 384) & 511];
      m = (m + k) & 511;
    }
    float mag = sqrtf(ar * ar + ai * ai);
    y[((size_t)f * BATCHN + b) * BINS + k] = (mag + imean[k]) * iscale[k];
  }
  // bin 256 (Nyquist): sum x[n]*(-1)^n, ai = 0
  {
    float part = xs[2 * tid] - xs[2 * tid + 1];
#pragma unroll
    for (int o = 32; o; o >>= 1) part += __shfl_down(part, o, 64);
    if ((tid & 63) == 0) red[tid >> 6] = part;
    __syncthreads();
    if (tid == 0) {
      float s = red[0] + red[1] + red[2] + red[3];
      y[((size_t)f * BATCHN + b) * BINS + 256] =
          (fabsf(s) + imean[256]) * iscale[256];
    }
  }
}

// ---------------- generic transpose ----------------
__global__ __launch_bounds__(256) void transpose_kernel(const float* __restrict__ in,
    float* __restrict__ out, int R, int C, long inBatch, long outBatch)
{
  __shared__ float tile[32][33];
  const float* ib = in + (size_t)blockIdx.z * inBatch;
  float* ob = out + (size_t)blockIdx.z * outBatch;
  int r0 = blockIdx.y * 32, c0 = blockIdx.x * 32;
  int tx = threadIdx.x & 31, ty = threadIdx.x >> 5;
  for (int i = ty; i < 32; i += 8) {
    int r = r0 + i, c = c0 + tx;
    if (r < R && c < C) tile[i][tx] = ib[(size_t)r * C + c];
  }
  __syncthreads();
  for (int i = ty; i < 32; i += 8) {
    int c = c0 + i, r = r0 + tx;
    if (r < R && c < C) ob[(size_t)c * R + r] = tile[tx][i];
  }
}

// ---------------- fp32 GEMM (+fused BN-tanh on A, optional gin3-layout store) ----
__device__ __forceinline__ void storeval(float* p, float v) { *p = v; }
__device__ __forceinline__ void storeval(unsigned short* p, float v) { *p = f2bf(v); }

template <typename OutT>
__global__ __launch_bounds__(256) void gemm_kernel(
    const float* __restrict__ A, long lda, long strideA,
    const float* __restrict__ B, long ldb, long strideB,
    OutT* __restrict__ C, long ldc, long strideC,
    int K, const float* __restrict__ bias,
    const float* __restrict__ trA, const float* __restrict__ trB, int ginmode)
{
  __shared__ float As[16][512];
  int bz = blockIdx.z;
  A += (size_t)bz * strideA; B += (size_t)bz * strideB; C += (size_t)bz * strideC;
  int rowb = blockIdx.x * 16;
  int colb = blockIdx.y * 512;
  int tid = threadIdx.x;
  for (int r = 0; r < 16; ++r)
    for (int k = tid; k < K; k += 256) {
      float v = A[(size_t)(rowb + r) * lda + k];
      if (trA) v = tanhf(trA[k] * v + trB[k]);
      As[r][k] = v;
    }
  __syncthreads();
  float acc0[16], acc1[16];
#pragma unroll
  for (int r = 0; r < 16; ++r) { acc0[r] = 0.f; acc1[r] = 0.f; }
  int c0 = colb + tid, c1 = colb + tid + 256;
  for (int k = 0; k < K; ++k) {
    float b0 = B[(size_t)k * ldb + c0];
    float b1 = B[(size_t)k * ldb + c1];
#pragma unroll
    for (int r = 0; r < 16; ++r) {
      acc0[r] = fmaf(As[r][k], b0, acc0[r]);
      acc1[r] = fmaf(As[r][k], b1, acc1[r]);
    }
  }
  float bs0 = bias ? bias[c0] : 0.f;
  float bs1 = bias ? bias[c1] : 0.f;
  if (ginmode) {
    unsigned short* Cg = (unsigned short*)C;
    for (int r = 0; r < 16; ++r) {
      int row = rowb + r; int t = row >> 3; int b = row & 7;
      { int dir = c0 >> 10, j = c0 & 1023;
        Cg[gin3_index(t, dir, b, j >> 8, j & 255)] = f2bf(acc0[r] + bs0); }
      { int dir = c1 >> 10, j = c1 & 1023;
        Cg[gin3_index(t, dir, b, j >> 8, j & 255)] = f2bf(acc1[r] + bs1); }
    }
  } else {
    for (int r = 0; r < 16; ++r) {
      storeval(C + (size_t)(rowb + r) * ldc + c0, acc0[r] + bs0);
      storeval(C + (size_t)(rowb + r) * ldc + c1, acc1[r] + bs1);
    }
  }
}

// ---------------- BatchNorm (training-mode batch stats) ----------------
__global__ __launch_bounds__(256) void bn_stats_kernel(const float* __restrict__ z,
                                                       float* __restrict__ stats)
{
  int rowb = blockIdx.x * 64;
  int c = threadIdx.x * 2;
  float s0 = 0, s1 = 0, q0 = 0, q1 = 0;
  for (int r = 0; r < 64; ++r) {
    const float* p = z + (size_t)(rowb + r) * 512 + c;
    float v0 = p[0], v1 = p[1];
    s0 += v0; s1 += v1; q0 += v0 * v0; q1 += v1 * v1;
  }
  atomicAdd(&stats[c], s0);       atomicAdd(&stats[c + 1], s1);
  atomicAdd(&stats[512 + c], q0); atomicAdd(&stats[512 + c + 1], q1);
}

__global__ void bn_fin_kernel(float* stats, const float* __restrict__ g,
                              const float* __restrict__ b)
{
  int h = threadIdx.x;  // 512 threads
  float mu  = stats[h] * (1.0f / 16384.0f);
  float var = stats[512 + h] * (1.0f / 16384.0f) - mu * mu;
  float a = g[h] * rsqrtf(var + 1e-5f);
  stats[1024 + h] = a;
  stats[1536 + h] = b[h] - mu * a;
}

// ---------------- text one-hot gate-input gather (gin3 layout) ----------------
__global__ __launch_bounds__(256) void text_gin_kernel(const int* __restrict__ idx,
    const float* __restrict__ twT, const float* __restrict__ tb,
    unsigned short* __restrict__ gin3t)
{
  size_t i = (size_t)blockIdx.x * 256 + threadIdx.x;
  if (i >= (size_t)LTXT * 8 * 2048) return;
  int j   = i & 1023;
  int dir = (i >> 10) & 1;
  int b   = (i >> 11) & 7;
  int l   = (int)(i >> 14);
  int v = idx[b * 512 + l];
  float val = twT[((size_t)dir * 44 + v) * 1024 + j] + tb[dir * 1024 + j];
  gin3t[gin3_index(l, dir, b, j >> 8, j & 255)] = f2bf(val);
}

// ---------------- single-WG-per-direction LSTM (i8 MFMA, weights in VGPRs) -----
// grid = 2*njobs blocks of 1024 threads (16 waves). block = (job, dir).
// Wave w owns units [w*16,(w+1)*16) x 4 gates; weights as i8 fragments in 64
// VGPRs/wave (Sw=256). h as i8 (Sh=127) in XOR-swizzled LDS, double-buffered.
// Gate redistribution via per-wave LDS round-trip (lane-linear writes,
// even-banked reads) instead of ds_bpermute. 2-deep gin prefetch (grA/grB).
__global__ __launch_bounds__(1024) void lstm_kernel(
    const unsigned short* __restrict__ gA, const float* __restrict__ whA,
    float* __restrict__ outA, long ostTA, long ostBA, int TA,
    const unsigned short* __restrict__ gB, const float* __restrict__ whB,
    float* __restrict__ outB, long ostTB, long ostBB, int TB)
{
  __shared__ unsigned char hlds[2][16][256];   // h i8, XOR-swizzled, double buffer
  __shared__ int redis[16][4][33][4];          // [wave][r][l32(pad 33)][gt] i32
  int job = blockIdx.x >> 1, dir = blockIdx.x & 1;
  const unsigned short* gin3 = job ? gB : gA;
  const float* whh = job ? whB : whA;
  float* out = job ? outB : outA;
  long ostT = job ? ostTB : ostTA;
  long ostB = job ? ostBB : ostBA;
  int T = job ? TB : TA;

  int tid = threadIdx.x;
  int w = tid >> 6;                 // 0..15
  int lane = tid & 63;
  int col = lane & 15, lg = lane >> 4;

  // ---- stage Whh -> i8 register fragments (one-time) ----
  int4v fb[4][4];
  {
    const float* wb = whh + (size_t)dir * 1024 * 256;
#pragma unroll
    for (int gt = 0; gt < 4; ++gt) {
      const float* wr = wb + (size_t)(gt * 256 + w * 16 + col) * 256 + lg * 16;
#pragma unroll
      for (int cc = 0; cc < 4; ++cc) {
        const float* p = wr + cc * 64;
        int4v v;
#pragma unroll
        for (int e = 0; e < 4; ++e) {
          unsigned wd = 0;
#pragma unroll
          for (int by = 0; by < 4; ++by) {
            float q = rintf(p[e * 4 + by] * 256.f);
            q = fminf(fmaxf(q, -127.f), 127.f);
            wd |= ((unsigned)((int)q & 255)) << (8 * by);
          }
          v[e] = (int)wd;
        }
        fb[gt][cc] = v;
      }
    }
  }

  {  // zero h buffers (rows 8..15 stay zero forever)
    int* hz = (int*)hlds;
    for (int i = tid; i < 2048; i += 1024) hz[i] = 0;
  }
  __syncthreads();

  float cst0 = 0.f, cst1 = 0.f;        // cell state for b = 2*lg, 2*lg+1
  int b0 = 2 * lg, b1 = 2 * lg + 1;
  int u = w * 16 + col;
  const float invS = 1.f / (256.f * 127.f);
  int r0i = (2 * lg) & 3;              // redis read r index for b0 (b1 = r0i+1)
  int l32r = col + (lg >> 1) * 16;     // redis read lane-linear index

  // per-lane gin base: elements (col*32 + b0*4), t stride = 16384 elems
  const unsigned short* glane = gin3 + (size_t)dir * 8192 + (size_t)w * 512 +
                                (size_t)(col * 32 + lg * 8);

  u16x8 grA, grB;
  {
    int t0 = dir ? (T - 1) : 0;
    int t1 = dir ? (T - 2) : 1;
    grA = *(const u16x8*)(glane + (size_t)t0 * 16384);
    grB = *(const u16x8*)(glane + (size_t)t1 * 16384);
  }

  auto step = [&](int s, u16x8& gr) {
    int t = dir ? (T - 1 - s) : s;
    int p = s & 1;

    // A fragments: h[batch=col][k-chunk] from hlds[p] (XOR-swizzled b128 reads)
    int4v fa[4];
#pragma unroll
    for (int cc = 0; cc < 4; ++cc) {
      int off = col * 256 + (((cc * 64) + lg * 16) ^ ((col & 7) << 4));
      fa[cc] = *(const int4v*)((const char*)&hlds[p][0][0] + off);
    }

    int4v acc[4];
#pragma unroll
    for (int gt = 0; gt < 4; ++gt) { int4v z = {0, 0, 0, 0}; acc[gt] = z; }
#pragma unroll
    for (int cc = 0; cc < 4; ++cc) {
#pragma unroll
      for (int gt = 0; gt < 4; ++gt) {
        acc[gt] = __builtin_amdgcn_mfma_i32_16x16x64_i8(fa[cc], fb[gt][cc],
                                                        acc[gt], 0, 0, 0);
      }
    }

    // redistribute via per-wave LDS round-trip (same wave: lgkmcnt only)
    if (lg < 2) {
#pragma unroll
      for (int r = 0; r < 4; ++r) {
        int4v tv; tv[0] = acc[0][r]; tv[1] = acc[1][r];
        tv[2] = acc[2][r]; tv[3] = acc[3][r];
        *(int4v*)&redis[w][r][col + lg * 16][0] = tv;
      }
    }
    int4v ga = *(const int4v*)&redis[w][r0i][l32r][0];
    int4v gb = *(const int4v*)&redis[w][r0i + 1][l32r][0];

    float g0[4], g1[4];
#pragma unroll
    for (int gt = 0; gt < 4; ++gt) {
      g0[gt] = bf2f(gr[gt])     + (float)ga[gt] * invS;
      g1[gt] = bf2f(gr[4 + gt]) + (float)gb[gt] * invS;
    }

    float gi0 = fsigm(g0[0]), gf0 = fsigm(g0[1]), gg0 = ftanh(g0[2]), go0 = fsigm(g0[3]);
    float gi1 = fsigm(g1[0]), gf1 = fsigm(g1[1]), gg1 = ftanh(g1[2]), go1 = fsigm(g1[3]);
    float c0 = gf0 * cst0 + gi0 * gg0; cst0 = c0;
    float c1 = gf1 * cst1 + gi1 * gg1; cst1 = c1;
    float h0 = go0 * ftanh(c0);
    float h1 = go1 * ftanh(c1);

    out[(size_t)t * ostT + (size_t)b0 * ostB + dir * 256 + u] = h0;
    out[(size_t)t * ostT + (size_t)b1 * ostB + dir * 256 + u] = h1;
    hlds[p ^ 1][b0][u ^ ((b0 & 7) << 4)] = (unsigned char)(int)rintf(h0 * 127.f);
    hlds[p ^ 1][b1][u ^ ((b1 & 7) << 4)] = (unsigned char)(int)rintf(h1 * 127.f);

    // prefetch gin for step s+2 (2 steps of latency hiding)
    if (s + 2 < T) {
      int tn = dir ? (T - 3 - s) : (s + 2);
      gr = *(const u16x8*)(glane + (size_t)tn * 16384);
    }
    __syncthreads();
  };

  for (int s = 0; s < T; s += 2) {
    step(s, grA);
    step(s + 1, grB);
  }
}

// ---------------- DTW (in-place over scores in d_out, row-prefetched) ----------
__global__ __launch_bounds__(256) void dtw_kernel(float* __restrict__ sc)
{
  __shared__ float P[513];
  int b = blockIdx.x, tid = threadIdx.x;
  for (int j = tid; j < 513; j += 256) P[j] = (j == 0) ? POSV : NEGV;
  __syncthreads();
  float* base = sc + (size_t)b * NFR * 512;
  float s0 = base[tid], s1 = base[tid + 256];   // preload row 0
  for (int n = 0; n < NFR; ++n) {
    float* row = base + (size_t)n * 512;
    float t0 = s0, t1 = s1;
    if (n + 1 < NFR) { s0 = row[512 + tid]; s1 = row[768 + tid]; }  // prefetch n+1
    float v0 = t0 + fmaxf(P[tid + 1], P[tid]);
    float v1 = t1 + fmaxf(P[tid + 257], P[tid + 256]);
    __syncthreads();
    P[tid + 1] = v0; P[tid + 257] = v1;
    if (tid == 0) P[0] = NEGV;
    row[tid] = v0; row[tid + 256] = v1;
    __syncthreads();
  }
}

// ---------------- launch ----------------
extern "C" void kernel_launch(void* const* d_in, const int* in_sizes, int n_in,
                              void* d_out, int out_size, void* d_ws, size_t ws_size,
                              hipStream_t stream) {
  const float* x_audio  = (const float*)d_in[0];
  const int*   text_idx = (const int*)d_in[1];
  const float* txt_wih  = (const float*)d_in[2];
  const float* txt_whh  = (const float*)d_in[3];
  const float* txt_b    = (const float*)d_in[4];
  const float* w_s      = (const float*)d_in[5];
  const float* fc1_w    = (const float*)d_in[6];
  const float* bn1_g    = (const float*)d_in[7];
  const float* bn1_b    = (const float*)d_in[8];
  const float* imean    = (const float*)d_in[9];
  const float* iscale   = (const float*)d_in[10];
  const float* ae_wih   = (const float*)d_in[11];
  const float* ae_whh   = (const float*)d_in[12];
  const float* ae_b     = (const float*)d_in[13];

  char* ws = (char*)d_ws;
  size_t off = 0;
  auto alloc = [&](size_t sz) { size_t o = off; off += (sz + 255) & ~255ull; return o; };
  size_t OFF_Y    = alloc(16384ull * 257 * 4);
  size_t OFF_WT   = alloc(257ull * 512 * 4);
  size_t OFF_TWT  = alloc(2ull * 44 * 1024 * 4);
  size_t OFF_WIHT = alloc(512ull * 2048 * 4);
  size_t OFF_Z    = alloc(16384ull * 512 * 4);
  size_t OFF_L1   = alloc(16384ull * 512 * 4);
  size_t OFF_L2   = alloc(16384ull * 512 * 4);   // also reused as gin3_text
  size_t OFF_TXT  = alloc(8ull * 512 * 512 * 4);
  size_t OFF_GIN  = alloc(16384ull * 2048 * 2);  // gin3_audio; reused later:
  size_t OFF_HTT  = OFF_GIN;                      //  htT (8.4MB)
  size_t OFF_SIDE = OFF_GIN + 8ull * 512 * 512 * 4; //  side (8.4MB)
  size_t OFF_STATS = alloc(2048ull * 4);
  (void)ws_size; (void)in_sizes; (void)n_in; (void)out_size;

  float* y       = (float*)(ws + OFF_Y);
  float* wT      = (float*)(ws + OFF_WT);
  float* twT     = (float*)(ws + OFF_TWT);
  float* wihT    = (float*)(ws + OFF_WIHT);
  float* z       = (float*)(ws + OFF_Z);
  float* l1out   = (float*)(ws + OFF_L1);
  float* l2out   = (float*)(ws + OFF_L2);
  float* textout = (float*)(ws + OFF_TXT);
  unsigned short* gin3a = (unsigned short*)(ws + OFF_GIN);
  unsigned short* gin3t = (unsigned short*)(ws + OFF_L2);  // dead until lstm2 out
  float* htT     = (float*)(ws + OFF_HTT);
  float* side    = (float*)(ws + OFF_SIDE);
  float* stats   = (float*)(ws + OFF_STATS);
  float* outp = (float*)d_out;

  zero_kernel<<<8, 256, 0, stream>>>((int*)(ws + OFF_STATS), 2048);

  stft_kernel<<<dim3(NFR, BATCHN), 256, 0, stream>>>(x_audio, imean, iscale, y);

  transpose_kernel<<<dim3(9, 16, 1), 256, 0, stream>>>(fc1_w, wT, 512, 257, 0, 0);
  transpose_kernel<<<dim3(2, 32, 2), 256, 0, stream>>>(txt_wih, twT, 1024, 44,
                                                       1024 * 44, 44 * 1024);

  // fc1: z = y @ wT
  gemm_kernel<float><<<dim3(1024, 1, 1), 256, 0, stream>>>(
      y, 257, 0, wT, 512, 0, z, 512, 0, 257, nullptr, nullptr, nullptr, 0);
  bn_stats_kernel<<<256, 256, 0, stream>>>(z, stats);
  bn_fin_kernel<<<1, 512, 0, stream>>>(stats, bn1_g, bn1_b);

  // text gin (gin3 layout)
  text_gin_kernel<<<32768, 256, 0, stream>>>(text_idx, twT, txt_b, gin3t);

  // audio layer-1 gin (BN+tanh fused into A staging), gin3 layout
  transpose_kernel<<<dim3(16, 64, 1), 256, 0, stream>>>(ae_wih, wihT, 2048, 512, 0, 0);
  gemm_kernel<unsigned short><<<dim3(1024, 4, 1), 256, 0, stream>>>(
      z, 512, 0, wihT, 2048, 0, gin3a, 0, 0, 512, ae_b,
      stats + 1024, stats + 1536, 1);

  // fused launch: audio layer-1 (job 0) + text encoder (job 1)
  lstm_kernel<<<4, 1024, 0, stream>>>(
      gin3a, ae_whh, l1out, 4096, 512, NFR,
      gin3t, txt_whh, textout, 512, 512 * 512, LTXT);

  // audio layer-2 gin
  transpose_kernel<<<dim3(16, 64, 1), 256, 0, stream>>>(
      ae_wih + 2ull * 1024 * 512, wihT, 2048, 512, 0, 0);
  gemm_kernel<unsigned short><<<dim3(1024, 4, 1), 256, 0, stream>>>(
      l1out, 512, 0, wihT, 2048, 0, gin3a, 0, 0, 512, ae_b + 2048,
      nullptr, nullptr, 1);

  lstm_kernel<<<2, 1024, 0, stream>>>(
      gin3a, ae_whh + 2ull * 1024 * 256, l2out, 4096, 512, NFR,
      gin3a, ae_whh + 2ull * 1024 * 256, l2out, 4096, 512, NFR);

  // side = w_s @ h_text^T  (per batch)
  transpose_kernel<<<dim3(16, 16, 8), 256, 0, stream>>>(textout, htT, 512, 512,
                                                        512 * 512, 512 * 512);
  gemm_kernel<float><<<dim3(32, 1, 8), 256, 0, stream>>>(
      w_s, 512, 0, htT, 512, 512 * 512, side, 512, 512 * 512, 512,
      nullptr, nullptr, nullptr, 0);

  // scores = x @ side -> d_out, then DTW in-place
  gemm_kernel<float><<<dim3(128, 1, 8), 256, 0, stream>>>(
      l2out, 4096, 512, side, 512, 512 * 512, outp, 512, (long)NFR * 512, 512,
      nullptr, nullptr, nullptr, 0);
  dtw_kernel<<<8, 256, 0, stream>>>(outp);
}

// Round 8
// 8595.081 us; speedup vs baseline: 3.0540x; 1.0707x over previous
//
#include <hip/hip_runtime.h>
#include <hip/hip_bf16.h>

// ---------------- constants ----------------
#define NFR    2048
#define BATCHN 8
#define NFFT   512
#define HOPSZ  256
#define BINS   257
#define HIDDEN 512
#define LTXT   512
#define TAUD   524544
#define NEGV  -100000.0f
#define POSV   200000.0f

using short8 = __attribute__((ext_vector_type(8))) short;
using u16x8  = __attribute__((ext_vector_type(8))) unsigned short;
using f32x4  = __attribute__((ext_vector_type(4))) float;
using int4v  = __attribute__((ext_vector_type(4))) int;

__device__ __forceinline__ unsigned short f2bf(float x) {
  union { float f; unsigned u; } v; v.f = x;
  unsigned u = v.u;
  u += 0x7fffu + ((u >> 16) & 1u);   // round-to-nearest-even
  return (unsigned short)(u >> 16);
}
__device__ __forceinline__ float bf2f(unsigned short h) {
  union { unsigned u; float f; } v; v.u = ((unsigned)h) << 16;
  return v.f;
}

__device__ __forceinline__ float fsigm(float x) {
  return __builtin_amdgcn_rcpf(1.f + __expf(-x));
}
__device__ __forceinline__ float ftanh(float x) {
  return 2.f * __builtin_amdgcn_rcpf(1.f + __expf(-2.f * x)) - 1.f;
}

// gin5 layout: per (t, dir, w): [bgrp(2)][ul(32)][br(4)][gt(4)] bf16 (1024/w-chunk)
// lane (w,col,lg) reads cells (batches bgrp*4+br, unit w*32+(lg>>1)*16+col) as
// one contiguous 32B chunk (16 bf16).
__device__ __forceinline__ size_t gin5_index(int t, int dir, int b, int gt, int u) {
  int w = u >> 5, ul = u & 31, bgrp = b >> 2, br = b & 3;
  return (((size_t)t * 2 + dir) * 8 + w) * 1024 +
         (size_t)((bgrp * 32 + ul) * 16 + br * 4 + gt);
}

// ---------------- zero fill ----------------
__global__ __launch_bounds__(256) void zero_kernel(int* p, int n) {
  int i = blockIdx.x * 256 + threadIdx.x;
  if (i < n) p[i] = 0;
}

// ---------------- STFT magnitude + input mean/scale ----------------
__global__ __launch_bounds__(256) void stft_kernel(const float* __restrict__ x,
    const float* __restrict__ imean, const float* __restrict__ iscale,
    float* __restrict__ y)
{
  __shared__ float tab[512];
  __shared__ float xs[512];
  __shared__ float red[4];
  int f = blockIdx.x, b = blockIdx.y, tid = threadIdx.x;
  for (int m = tid; m < 512; m += 256)
    tab[m] = cosf(6.283185307179586e0f / 512.0f * (float)m);
  __syncthreads();
  const float* xb = x + (size_t)b * TAUD + (size_t)f * HOPSZ;
  for (int n = tid; n < 512; n += 256)
    xs[n] = xb[n] * 0.5f * (1.0f - tab[n]);   // periodic hann
  __syncthreads();
  // bins 0..255 (one per thread)
  {
    int k = tid;
    float ar = 0.f, ai = 0.f;
    int m = 0;
    for (int n = 0; n < 512; ++n) {
      float xv = xs[n];
      ar += xv * tab[m];
      ai += xv * tab[(m + 384) & 511];
      m = (m + k) & 511;
    }
    float mag = sqrtf(ar * ar + ai * ai);
    y[((size_t)f * BATCHN + b) * BINS + k] = (mag + imean[k]) * iscale[k];
  }
  // bin 256 (Nyquist): sum x[n]*(-1)^n, ai = 0
  {
    float part = xs[2 * tid] - xs[2 * tid + 1];
#pragma unroll
    for (int o = 32; o; o >>= 1) part += __shfl_down(part, o, 64);
    if ((tid & 63) == 0) red[tid >> 6] = part;
    __syncthreads();
    if (tid == 0) {
      float s = red[0] + red[1] + red[2] + red[3];
      y[((size_t)f * BATCHN + b) * BINS + 256] =
          (fabsf(s) + imean[256]) * iscale[256];
    }
  }
}

// ---------------- generic transpose ----------------
__global__ __launch_bounds__(256) void transpose_kernel(const float* __restrict__ in,
    float* __restrict__ out, int R, int C, long inBatch, long outBatch)
{
  __shared__ float tile[32][33];
  const float* ib = in + (size_t)blockIdx.z * inBatch;
  float* ob = out + (size_t)blockIdx.z * outBatch;
  int r0 = blockIdx.y * 32, c0 = blockIdx.x * 32;
  int tx = threadIdx.x & 31, ty = threadIdx.x >> 5;
  for (int i = ty; i < 32; i += 8) {
    int r = r0 + i, c = c0 + tx;
    if (r < R && c < C) tile[i][tx] = ib[(size_t)r * C + c];
  }
  __syncthreads();
  for (int i = ty; i < 32; i += 8) {
    int c = c0 + i, r = r0 + tx;
    if (r < R && c < C) ob[(size_t)c * R + r] = tile[tx][i];
  }
}

// ---------------- fp32 GEMM (+fused BN-tanh on A, optional gin5-layout store) ----
__device__ __forceinline__ void storeval(float* p, float v) { *p = v; }
__device__ __forceinline__ void storeval(unsigned short* p, float v) { *p = f2bf(v); }

template <typename OutT>
__global__ __launch_bounds__(256) void gemm_kernel(
    const float* __restrict__ A, long lda, long strideA,
    const float* __restrict__ B, long ldb, long strideB,
    OutT* __restrict__ C, long ldc, long strideC,
    int K, const float* __restrict__ bias,
    const float* __restrict__ trA, const float* __restrict__ trB, int ginmode)
{
  __shared__ float As[16][512];
  int bz = blockIdx.z;
  A += (size_t)bz * strideA; B += (size_t)bz * strideB; C += (size_t)bz * strideC;
  int rowb = blockIdx.x * 16;
  int colb = blockIdx.y * 512;
  int tid = threadIdx.x;
  for (int r = 0; r < 16; ++r)
    for (int k = tid; k < K; k += 256) {
      float v = A[(size_t)(rowb + r) * lda + k];
      if (trA) v = tanhf(trA[k] * v + trB[k]);
      As[r][k] = v;
    }
  __syncthreads();
  float acc0[16], acc1[16];
#pragma unroll
  for (int r = 0; r < 16; ++r) { acc0[r] = 0.f; acc1[r] = 0.f; }
  int c0 = colb + tid, c1 = colb + tid + 256;
  for (int k = 0; k < K; ++k) {
    float b0 = B[(size_t)k * ldb + c0];
    float b1 = B[(size_t)k * ldb + c1];
#pragma unroll
    for (int r = 0; r < 16; ++r) {
      acc0[r] = fmaf(As[r][k], b0, acc0[r]);
      acc1[r] = fmaf(As[r][k], b1, acc1[r]);
    }
  }
  float bs0 = bias ? bias[c0] : 0.f;
  float bs1 = bias ? bias[c1] : 0.f;
  if (ginmode) {
    unsigned short* Cg = (unsigned short*)C;
    for (int r = 0; r < 16; ++r) {
      int row = rowb + r; int t = row >> 3; int b = row & 7;
      { int dir = c0 >> 10, j = c0 & 1023;
        Cg[gin5_index(t, dir, b, j >> 8, j & 255)] = f2bf(acc0[r] + bs0); }
      { int dir = c1 >> 10, j = c1 & 1023;
        Cg[gin5_index(t, dir, b, j >> 8, j & 255)] = f2bf(acc1[r] + bs1); }
    }
  } else {
    for (int r = 0; r < 16; ++r) {
      storeval(C + (size_t)(rowb + r) * ldc + c0, acc0[r] + bs0);
      storeval(C + (size_t)(rowb + r) * ldc + c1, acc1[r] + bs1);
    }
  }
}

// ---------------- BatchNorm (training-mode batch stats) ----------------
__global__ __launch_bounds__(256) void bn_stats_kernel(const float* __restrict__ z,
                                                       float* __restrict__ stats)
{
  int rowb = blockIdx.x * 64;
  int c = threadIdx.x * 2;
  float s0 = 0, s1 = 0, q0 = 0, q1 = 0;
  for (int r = 0; r < 64; ++r) {
    const float* p = z + (size_t)(rowb + r) * 512 + c;
    float v0 = p[0], v1 = p[1];
    s0 += v0; s1 += v1; q0 += v0 * v0; q1 += v1 * v1;
  }
  atomicAdd(&stats[c], s0);       atomicAdd(&stats[c + 1], s1);
  atomicAdd(&stats[512 + c], q0); atomicAdd(&stats[512 + c + 1], q1);
}

__global__ void bn_fin_kernel(float* stats, const float* __restrict__ g,
                              const float* __restrict__ b)
{
  int h = threadIdx.x;  // 512 threads
  float mu  = stats[h] * (1.0f / 16384.0f);
  float var = stats[512 + h] * (1.0f / 16384.0f) - mu * mu;
  float a = g[h] * rsqrtf(var + 1e-5f);
  stats[1024 + h] = a;
  stats[1536 + h] = b[h] - mu * a;
}

// ---------------- text one-hot gate-input gather (gin5 layout) ----------------
__global__ __launch_bounds__(256) void text_gin_kernel(const int* __restrict__ idx,
    const float* __restrict__ twT, const float* __restrict__ tb,
    unsigned short* __restrict__ gin5t)
{
  size_t i = (size_t)blockIdx.x * 256 + threadIdx.x;
  if (i >= (size_t)LTXT * 8 * 2048) return;
  int j   = i & 1023;
  int dir = (i >> 10) & 1;
  int b   = (i >> 11) & 7;
  int l   = (int)(i >> 14);
  int v = idx[b * 512 + l];
  float val = twT[((size_t)dir * 44 + v) * 1024 + j] + tb[dir * 1024 + j];
  gin5t[gin5_index(l, dir, b, j >> 8, j & 255)] = f2bf(val);
}

// ---------------- single-WG-per-direction LSTM (i8 MFMA, 8 waves) -------------
// grid = 2*njobs blocks of 512 threads. block = (job, dir).
// Wave w owns units [w*32,(w+1)*32) x 4 gates; weights as i8 fragments in 128
// regs/wave. h as i8 in XOR-swizzled LDS, double-buffered.
// Gate redistribution is register-only: v_permlane32_swap_b32 pairs the uh0/uh1
// accumulators so every lane gets 4 cells -- zero LDS redis traffic. Per-step
// LDS = 8 waves x 4KB fa reads only. Pointer-incremented gin/out addressing.
#define LSTM_STEP(P, gv0, gv1)                                                  \
  {                                                                             \
    int4v fa[4];                                                                \
    _Pragma("unroll")                                                           \
    for (int cc = 0; cc < 4; ++cc) {                                            \
      int off = col * 256 + (((cc * 64) + lg * 16) ^ ((col & 7) << 4));         \
      fa[cc] = *(const int4v*)((const char*)&hlds[P][0][0] + off);              \
    }                                                                           \
    int4v acc[8];                                                               \
    _Pragma("unroll")                                                           \
    for (int n = 0; n < 8; ++n) { int4v z = {0, 0, 0, 0}; acc[n] = z; }         \
    _Pragma("unroll")                                                           \
    for (int cc = 0; cc < 4; ++cc) {                                            \
      _Pragma("unroll")                                                         \
      for (int n = 0; n < 8; ++n)                                               \
        acc[n] = __builtin_amdgcn_mfma_i32_16x16x64_i8(fa[cc], fb[n][cc],       \
                                                       acc[n], 0, 0, 0);        \
    }                                                                           \
    _Pragma("unroll")                                                           \
    for (int r = 0; r < 4; ++r) {                                               \
      float g[4];                                                               \
      _Pragma("unroll")                                                         \
      for (int gt = 0; gt < 4; ++gt) {                                          \
        int av = acc[gt * 2][r], bv = acc[gt * 2 + 1][r];                       \
        asm("v_permlane32_swap_b32 %0, %1" : "+v"(av), "+v"(bv));               \
        unsigned short gu = (r < 2) ? (gv0)[(r & 1) * 4 + gt]                   \
                                    : (gv1)[(r & 1) * 4 + gt];                  \
        g[gt] = fmaf((float)av, invS, bf2f(gu));                                \
      }                                                                         \
      float si = fsigm(g[0]), sf = fsigm(g[1]);                                 \
      float tg = ftanh(g[2]), so = fsigm(g[3]);                                 \
      float c = sf * cst[r] + si * tg; cst[r] = c;                              \
      float h = so * ftanh(c);                                                  \
      *ob[r] = h; ob[r] += tstep;                                               \
      int q = (int)rintf(h * 127.f);                                            \
      int b = bbase + r;                                                        \
      hlds[(P) ^ 1][b][u ^ ((b & 7) << 4)] = (unsigned char)q;                  \
    }                                                                           \
    __syncthreads();                                                            \
  }

__global__ __launch_bounds__(512) void lstm_kernel(
    const unsigned short* __restrict__ gA, const float* __restrict__ whA,
    float* __restrict__ outA, long ostTA, long ostBA, int TA,
    const unsigned short* __restrict__ gB, const float* __restrict__ whB,
    float* __restrict__ outB, long ostTB, long ostBB, int TB)
{
  __shared__ unsigned char hlds[2][16][256];   // h i8, XOR-swizzled, double buffer
  int job = blockIdx.x >> 1, dir = blockIdx.x & 1;
  const unsigned short* gin = job ? gB : gA;
  const float* whh = job ? whB : whA;
  float* out = job ? outB : outA;
  long ostT = job ? ostTB : ostTA;
  long ostB = job ? ostBB : ostBA;
  int T = job ? TB : TA;

  int tid = threadIdx.x;
  int w = tid >> 6;                 // 0..7
  int lane = tid & 63;
  int col = lane & 15, lg = lane >> 4;

  // ---- stage Whh -> i8 register fragments (one-time) ----
  // tile n=(gt,uh): B col c = gate row gt*256 + w*32 + uh*16 + c; k = cc*64+lg*16+j
  int4v fb[8][4];
  {
    const float* wb = whh + (size_t)dir * 1024 * 256;
#pragma unroll
    for (int n = 0; n < 8; ++n) {
      int gt = n >> 1, uh = n & 1;
      const float* wr = wb + (size_t)(gt * 256 + w * 32 + uh * 16 + col) * 256 + lg * 16;
#pragma unroll
      for (int cc = 0; cc < 4; ++cc) {
        const float* p = wr + cc * 64;
        int4v v;
#pragma unroll
        for (int e = 0; e < 4; ++e) {
          unsigned wd = 0;
#pragma unroll
          for (int by = 0; by < 4; ++by) {
            float q = rintf(p[e * 4 + by] * 256.f);
            q = fminf(fmaxf(q, -127.f), 127.f);
            wd |= ((unsigned)((int)q & 255)) << (8 * by);
          }
          v[e] = (int)wd;
        }
        fb[n][cc] = v;
      }
    }
  }

  {  // zero h buffers (rows 8..15 stay zero forever)
    int* hz = (int*)hlds;
    for (int i = tid; i < 2048; i += 512) hz[i] = 0;
  }
  __syncthreads();

  const float invS = 1.f / (256.f * 127.f);
  float cst[4] = {0.f, 0.f, 0.f, 0.f};
  int u = w * 32 + (lg >> 1) * 16 + col;   // this lane's unit
  int bbase = (lg & 1) * 4;                // this lane's batch group

  long tstep = dir ? -ostT : ostT;
  float* ob[4];
  {
    int t0 = dir ? (T - 1) : 0;
    float* o = out + (size_t)t0 * ostT + dir * 256 + u;
#pragma unroll
    for (int r = 0; r < 4; ++r) ob[r] = o + (size_t)(bbase + r) * ostB;
  }

  const unsigned short* glane = gin + (size_t)dir * 8192 + (size_t)w * 1024 +
      (size_t)(((lg & 1) * 32 + (lg >> 1) * 16 + col) * 16);
  long gstep2 = (dir ? -2l : 2l) * 16384;
  const unsigned short* gpA = glane + (size_t)(dir ? (T - 1) : 0) * 16384;
  const unsigned short* gpB = glane + (size_t)(dir ? (T - 2) : 1) * 16384;
  u16x8 grA0 = *(const u16x8*)gpA, grA1 = *(const u16x8*)(gpA + 8);
  u16x8 grB0 = *(const u16x8*)gpB, grB1 = *(const u16x8*)(gpB + 8);
  gpA += gstep2; gpB += gstep2;

  for (int s = 0; s < T; s += 2) {
    u16x8 nA0 = *(const u16x8*)gpA, nA1 = *(const u16x8*)(gpA + 8);
    u16x8 nB0 = *(const u16x8*)gpB, nB1 = *(const u16x8*)(gpB + 8);
    gpA += gstep2; gpB += gstep2;
    LSTM_STEP(0, grA0, grA1)
    LSTM_STEP(1, grB0, grB1)
    grA0 = nA0; grA1 = nA1; grB0 = nB0; grB1 = nB1;
  }
}

// ---------------- DTW (in-place over scores in d_out, row-prefetched) ----------
__global__ __launch_bounds__(256) void dtw_kernel(float* __restrict__ sc)
{
  __shared__ float P[513];
  int b = blockIdx.x, tid = threadIdx.x;
  for (int j = tid; j < 513; j += 256) P[j] = (j == 0) ? POSV : NEGV;
  __syncthreads();
  float* base = sc + (size_t)b * NFR * 512;
  float s0 = base[tid], s1 = base[tid + 256];   // preload row 0
  for (int n = 0; n < NFR; ++n) {
    float* row = base + (size_t)n * 512;
    float t0 = s0, t1 = s1;
    if (n + 1 < NFR) { s0 = row[512 + tid]; s1 = row[768 + tid]; }  // prefetch n+1
    float v0 = t0 + fmaxf(P[tid + 1], P[tid]);
    float v1 = t1 + fmaxf(P[tid + 257], P[tid + 256]);
    __syncthreads();
    P[tid + 1] = v0; P[tid + 257] = v1;
    if (tid == 0) P[0] = NEGV;
    row[tid] = v0; row[tid + 256] = v1;
    __syncthreads();
  }
}

// ---------------- launch ----------------
extern "C" void kernel_launch(void* const* d_in, const int* in_sizes, int n_in,
                              void* d_out, int out_size, void* d_ws, size_t ws_size,
                              hipStream_t stream) {
  const float* x_audio  = (const float*)d_in[0];
  const int*   text_idx = (const int*)d_in[1];
  const float* txt_wih  = (const float*)d_in[2];
  const float* txt_whh  = (const float*)d_in[3];
  const float* txt_b    = (const float*)d_in[4];
  const float* w_s      = (const float*)d_in[5];
  const float* fc1_w    = (const float*)d_in[6];
  const float* bn1_g    = (const float*)d_in[7];
  const float* bn1_b    = (const float*)d_in[8];
  const float* imean    = (const float*)d_in[9];
  const float* iscale   = (const float*)d_in[10];
  const float* ae_wih   = (const float*)d_in[11];
  const float* ae_whh   = (const float*)d_in[12];
  const float* ae_b     = (const float*)d_in[13];

  char* ws = (char*)d_ws;
  size_t off = 0;
  auto alloc = [&](size_t sz) { size_t o = off; off += (sz + 255) & ~255ull; return o; };
  size_t OFF_Y    = alloc(16384ull * 257 * 4);
  size_t OFF_WT   = alloc(257ull * 512 * 4);
  size_t OFF_TWT  = alloc(2ull * 44 * 1024 * 4);
  size_t OFF_WIHT = alloc(512ull * 2048 * 4);
  size_t OFF_Z    = alloc(16384ull * 512 * 4);
  size_t OFF_L1   = alloc(16384ull * 512 * 4);
  size_t OFF_L2   = alloc(16384ull * 512 * 4);   // also reused as gin5_text
  size_t OFF_TXT  = alloc(8ull * 512 * 512 * 4);
  size_t OFF_GIN  = alloc(16384ull * 2048 * 2);  // gin5_audio; reused later:
  size_t OFF_HTT  = OFF_GIN;                      //  htT (8.4MB)
  size_t OFF_SIDE = OFF_GIN + 8ull * 512 * 512 * 4; //  side (8.4MB)
  size_t OFF_PAD  = alloc(262144);                // OOB-prefetch pad after GIN
  size_t OFF_STATS = alloc(2048ull * 4);
  (void)ws_size; (void)in_sizes; (void)n_in; (void)out_size; (void)OFF_PAD;

  float* y       = (float*)(ws + OFF_Y);
  float* wT      = (float*)(ws + OFF_WT);
  float* twT     = (float*)(ws + OFF_TWT);
  float* wihT    = (float*)(ws + OFF_WIHT);
  float* z       = (float*)(ws + OFF_Z);
  float* l1out   = (float*)(ws + OFF_L1);
  float* l2out   = (float*)(ws + OFF_L2);
  float* textout = (float*)(ws + OFF_TXT);
  unsigned short* gin5a = (unsigned short*)(ws + OFF_GIN);
  unsigned short* gin5t = (unsigned short*)(ws + OFF_L2);  // dead until lstm2 out
  float* htT     = (float*)(ws + OFF_HTT);
  float* side    = (float*)(ws + OFF_SIDE);
  float* stats   = (float*)(ws + OFF_STATS);
  float* outp = (float*)d_out;

  zero_kernel<<<8, 256, 0, stream>>>((int*)(ws + OFF_STATS), 2048);

  stft_kernel<<<dim3(NFR, BATCHN), 256, 0, stream>>>(x_audio, imean, iscale, y);

  transpose_kernel<<<dim3(9, 16, 1), 256, 0, stream>>>(fc1_w, wT, 512, 257, 0, 0);
  transpose_kernel<<<dim3(2, 32, 2), 256, 0, stream>>>(txt_wih, twT, 1024, 44,
                                                       1024 * 44, 44 * 1024);

  // fc1: z = y @ wT
  gemm_kernel<float><<<dim3(1024, 1, 1), 256, 0, stream>>>(
      y, 257, 0, wT, 512, 0, z, 512, 0, 257, nullptr, nullptr, nullptr, 0);
  bn_stats_kernel<<<256, 256, 0, stream>>>(z, stats);
  bn_fin_kernel<<<1, 512, 0, stream>>>(stats, bn1_g, bn1_b);

  // text gin (gin5 layout)
  text_gin_kernel<<<32768, 256, 0, stream>>>(text_idx, twT, txt_b, gin5t);

  // audio layer-1 gin (BN+tanh fused into A staging), gin5 layout
  transpose_kernel<<<dim3(16, 64, 1), 256, 0, stream>>>(ae_wih, wihT, 2048, 512, 0, 0);
  gemm_kernel<unsigned short><<<dim3(1024, 4, 1), 256, 0, stream>>>(
      z, 512, 0, wihT, 2048, 0, gin5a, 0, 0, 512, ae_b,
      stats + 1024, stats + 1536, 1);

  // fused launch: audio layer-1 (job 0) + text encoder (job 1)
  lstm_kernel<<<4, 512, 0, stream>>>(
      gin5a, ae_whh, l1out, 4096, 512, NFR,
      gin5t, txt_whh, textout, 512, 512 * 512, LTXT);

  // audio layer-2 gin
  transpose_kernel<<<dim3(16, 64, 1), 256, 0, stream>>>(
      ae_wih + 2ull * 1024 * 512, wihT, 2048, 512, 0, 0);
  gemm_kernel<unsigned short><<<dim3(1024, 4, 1), 256, 0, stream>>>(
      l1out, 512, 0, wihT, 2048, 0, gin5a, 0, 0, 512, ae_b + 2048,
      nullptr, nullptr, 1);

  lstm_kernel<<<2, 512, 0, stream>>>(
      gin5a, ae_whh + 2ull * 1024 * 256, l2out, 4096, 512, NFR,
      gin5a, ae_whh + 2ull * 1024 * 256, l2out, 4096, 512, NFR);

  // side = w_s @ h_text^T  (per batch)
  transpose_kernel<<<dim3(16, 16, 8), 256, 0, stream>>>(textout, htT, 512, 512,
                                                        512 * 512, 512 * 512);
  gemm_kernel<float><<<dim3(32, 1, 8), 256, 0, stream>>>(
      w_s, 512, 0, htT, 512, 512 * 512, side, 512, 512 * 512, 512,
      nullptr, nullptr, nullptr, 0);

  // scores = x @ side -> d_out, then DTW in-place
  gemm_kernel<float><<<dim3(128, 1, 8), 256, 0, stream>>>(
      l2out, 4096, 512, side, 512, 512 * 512, outp, 512, (long)NFR * 512, 512,
      nullptr, nullptr, nullptr, 0);
  dtw_kernel<<<8, 256, 0, stream>>>(outp);
}